// Round 1
// baseline (341.810 us; speedup 1.0000x reference)
//
#include <hip/hip_runtime.h>

#define NN 10000
#define NE 320000

// ---------- edge index access (int32 vs int64 auto-detect) ----------
__device__ __forceinline__ int eread(const void* p, int is64, int i) {
    if (is64) return (int)((const long long*)p)[i];
    return ((const int*)p)[i];
}

__global__ void k_detect(const unsigned int* __restrict__ idx, int* __restrict__ flag) {
    if (threadIdx.x == 0 && blockIdx.x == 0) {
        int all0 = 1;
        for (int j = 1; j < 257; j += 2)
            if (idx[j] != 0u) { all0 = 0; break; }
        *flag = all0;  // 1 => int64 (high words all zero), 0 => int32
    }
}

__global__ void k_zero(float* __restrict__ p, int n) {
    int i = blockIdx.x * blockDim.x + threadIdx.x;
    if (i < n) p[i] = 0.0f;
}

// ---------- Layer-1 GEMM: h1[N][512] = x[N][128] @ W1[128][512] ----------
#define TN 16
__global__ __launch_bounds__(256) void k_gemm1(const float* __restrict__ x,
                                               const float* __restrict__ W1,
                                               float* __restrict__ h1) {
    __shared__ float xs[TN * 128];
    const int t = threadIdx.x;
    const int n0 = blockIdx.x * TN;
    {   // stage x tile (2048 floats) coalesced
        const float4* src = (const float4*)(x + (size_t)n0 * 128);
        float4* dst = (float4*)xs;
        dst[t] = src[t];
        dst[t + 256] = src[t + 256];
    }
    __syncthreads();
    float acc0[TN], acc1[TN];
#pragma unroll
    for (int n = 0; n < TN; n++) { acc0[n] = 0.f; acc1[n] = 0.f; }
    const int j0 = t;  // columns t and t+256
    for (int k = 0; k < 128; k += 4) {
        const float* wr = W1 + (size_t)k * 512 + j0;
        float w00 = wr[0],        w01 = wr[512],        w02 = wr[1024],        w03 = wr[1536];
        float w10 = wr[256],      w11 = wr[512 + 256],  w12 = wr[1024 + 256],  w13 = wr[1536 + 256];
#pragma unroll
        for (int n = 0; n < TN; n++) {
            float4 xv = *(const float4*)&xs[n * 128 + k];
            acc0[n] += xv.x * w00 + xv.y * w01 + xv.z * w02 + xv.w * w03;
            acc1[n] += xv.x * w10 + xv.y * w11 + xv.z * w12 + xv.w * w13;
        }
    }
#pragma unroll
    for (int n = 0; n < TN; n++) {
        h1[(size_t)(n0 + n) * 512 + j0]       = acc0[n];
        h1[(size_t)(n0 + n) * 512 + j0 + 256] = acc1[n];
    }
}

// ---------- per-node attention terms hl1/hr1 [N][4] ----------
__global__ __launch_bounds__(256) void k_hlhr1(const float* __restrict__ h1,
                                               const float* __restrict__ a1,
                                               float* __restrict__ hl1,
                                               float* __restrict__ hr1) {
    const int t = threadIdx.x, lane = t & 63, w = t >> 6;
    const int i = blockIdx.x * 4 + w;
    const int head = lane >> 4, dbase = (lane & 15) * 8;
    const float* hp = h1 + (size_t)i * 512 + lane * 8;
    float4 v0 = *(const float4*)hp;
    float4 v1 = *(const float4*)(hp + 4);
    const float* al = a1 + head * 256 + dbase;
    const float* ar = al + 128;
    float pl = v0.x * al[0] + v0.y * al[1] + v0.z * al[2] + v0.w * al[3]
             + v1.x * al[4] + v1.y * al[5] + v1.z * al[6] + v1.w * al[7];
    float pr = v0.x * ar[0] + v0.y * ar[1] + v0.z * ar[2] + v0.w * ar[3]
             + v1.x * ar[4] + v1.y * ar[5] + v1.z * ar[6] + v1.w * ar[7];
#pragma unroll
    for (int off = 1; off < 16; off <<= 1) {
        pl += __shfl_xor(pl, off);
        pr += __shfl_xor(pr, off);
    }
    if ((lane & 15) == 0) {
        hl1[i * 4 + head] = pl;
        hr1[i * 4 + head] = pr;
    }
}

// ---------- edge pass 1: degree histogram (by col) + softmax denom z1 (by row) ----------
__global__ __launch_bounds__(256) void k_edge1(const void* __restrict__ ei, const int* __restrict__ flag,
                                               const float* __restrict__ hl1, const float* __restrict__ hr1,
                                               float* __restrict__ z1, int* __restrict__ deg) {
    const int is64 = *flag;
    const int e = blockIdx.x * blockDim.x + threadIdx.x;
    if (e >= NE) return;
    const int r = eread(ei, is64, e);
    const int c = eread(ei, is64, NE + e);
    atomicAdd(deg + c, 1);
    float4 l4 = *(const float4*)&hl1[r * 4];
    float4 r4 = *(const float4*)&hr1[c * 4];
    atomicAdd(&z1[r * 4 + 0], expf(l4.x + r4.x));
    atomicAdd(&z1[r * 4 + 1], expf(l4.y + r4.y));
    atomicAdd(&z1[r * 4 + 2], expf(l4.z + r4.z));
    atomicAdd(&z1[r * 4 + 3], expf(l4.w + r4.w));
}

// ---------- exclusive scan of deg -> start, cursor (single block) ----------
__global__ __launch_bounds__(256) void k_scan(const int* __restrict__ deg,
                                              int* __restrict__ start, int* __restrict__ cursor) {
    const int t = threadIdx.x;
    int loc[40];
    const int base = t * 40;
    int sum = 0;
#pragma unroll
    for (int j = 0; j < 40; j++) {
        int i = base + j;
        int v = (i < NN) ? deg[i] : 0;
        loc[j] = sum;
        sum += v;
    }
    const int lane = t & 63, w = t >> 6;
    int x = sum;
#pragma unroll
    for (int off = 1; off < 64; off <<= 1) {
        int y = __shfl_up(x, off);
        if (lane >= off) x += y;
    }
    __shared__ int ssum[4];
    if (lane == 63) ssum[w] = x;
    __syncthreads();
    int woff = 0;
#pragma unroll
    for (int k = 0; k < 4; k++)
        if (k < w) woff += ssum[k];
    const int excl = woff + x - sum;
#pragma unroll
    for (int j = 0; j < 40; j++) {
        int i = base + j;
        if (i < NN) {
            int v = excl + loc[j];
            start[i] = v;
            cursor[i] = v;
        }
    }
}

// ---------- scatter: CSR by col, payload = row index ----------
__global__ __launch_bounds__(256) void k_scatter(const void* __restrict__ ei, const int* __restrict__ flag,
                                                 int* __restrict__ cursor, int* __restrict__ csr_row) {
    const int is64 = *flag;
    const int e = blockIdx.x * blockDim.x + threadIdx.x;
    if (e >= NE) return;
    const int r = eread(ei, is64, e);
    const int c = eread(ei, is64, NE + e);
    const int pos = atomicAdd(cursor + c, 1);
    csr_row[pos] = r;
}

// ---------- L1 aggregation + ELU + head-mean: h1m[N][128] ----------
__global__ __launch_bounds__(256) void k_agg1(const float* __restrict__ h1,
                                              const float* __restrict__ hl1, const float* __restrict__ hr1,
                                              const float* __restrict__ z1,
                                              const int* __restrict__ start, const int* __restrict__ deg,
                                              const int* __restrict__ csr_row,
                                              float* __restrict__ h1m) {
    const int t = threadIdx.x, lane = t & 63, w = t >> 6;
    const int i = blockIdx.x * 4 + w;
    const int head = lane >> 4;
    const float hrv = hr1[i * 4 + head];
    const int s0 = start[i], dg = deg[i];
    float4 a0 = {0.f, 0.f, 0.f, 0.f};
    float4 a1v = {0.f, 0.f, 0.f, 0.f};
    for (int p = s0; p < s0 + dg; ++p) {
        const int r = csr_row[p];
        const float s = hl1[r * 4 + head] + hrv;
        const float al = expf(s) / z1[r * 4 + head];
        const float* hp = h1 + (size_t)r * 512 + lane * 8;
        float4 v0 = *(const float4*)hp;
        float4 v1 = *(const float4*)(hp + 4);
        a0.x += al * v0.x; a0.y += al * v0.y; a0.z += al * v0.z; a0.w += al * v0.w;
        a1v.x += al * v1.x; a1v.y += al * v1.y; a1v.z += al * v1.z; a1v.w += al * v1.w;
    }
    float vals[8] = {a0.x, a0.y, a0.z, a0.w, a1v.x, a1v.y, a1v.z, a1v.w};
#pragma unroll
    for (int j = 0; j < 8; j++) {
        float v = vals[j];
        v = (v > 0.f) ? v : (expf(v) - 1.0f);   // ELU
        v += __shfl_xor(v, 16);                  // sum heads 0<->1, 2<->3
        v += __shfl_xor(v, 32);                  // sum pairs
        vals[j] = v * 0.25f;                     // mean over 4 heads
    }
    if (lane < 16) {
        float* op = h1m + (size_t)i * 128 + lane * 8;
        float4 o0 = {vals[0], vals[1], vals[2], vals[3]};
        float4 o1 = {vals[4], vals[5], vals[6], vals[7]};
        *(float4*)op = o0;
        *(float4*)(op + 4) = o1;
    }
}

// ---------- Layer-2 GEMM + attention terms ----------
__global__ __launch_bounds__(256) void k_gemm2(const float* __restrict__ h1m, const float* __restrict__ W2,
                                               const float* __restrict__ a2,
                                               float* __restrict__ h2, float* __restrict__ hl2,
                                               float* __restrict__ hr2) {
    __shared__ float sh[4][128];
    const int t = threadIdx.x, lane = t & 63, w = t >> 6;
    const int i = blockIdx.x * 4 + w;
    sh[w][lane]      = h1m[(size_t)i * 128 + lane];
    sh[w][lane + 64] = h1m[(size_t)i * 128 + 64 + lane];
    __syncthreads();
    float acc = 0.f;
    if (lane < 22) {
        for (int k = 0; k < 128; k++)
            acc += sh[w][k] * W2[k * 22 + lane];
        h2[(size_t)i * 22 + lane] = acc;
    }
    float pl = (lane < 22) ? acc * a2[lane] : 0.f;
    float pr = (lane < 22) ? acc * a2[22 + lane] : 0.f;
#pragma unroll
    for (int off = 1; off < 64; off <<= 1) {
        pl += __shfl_xor(pl, off);
        pr += __shfl_xor(pr, off);
    }
    if (lane == 0) {
        hl2[i] = pl;
        hr2[i] = pr;
    }
}

// ---------- edge pass 2: z2 denom ----------
__global__ __launch_bounds__(256) void k_edge2(const void* __restrict__ ei, const int* __restrict__ flag,
                                               const float* __restrict__ hl2, const float* __restrict__ hr2,
                                               float* __restrict__ z2) {
    const int is64 = *flag;
    const int e = blockIdx.x * blockDim.x + threadIdx.x;
    if (e >= NE) return;
    const int r = eread(ei, is64, e);
    const int c = eread(ei, is64, NE + e);
    atomicAdd(&z2[r], expf(hl2[r] + hr2[c]));
}

// ---------- L2 aggregation -> output [N][22] ----------
__global__ __launch_bounds__(256) void k_agg2(const float* __restrict__ h2,
                                              const float* __restrict__ hl2, const float* __restrict__ hr2,
                                              const float* __restrict__ z2,
                                              const int* __restrict__ start, const int* __restrict__ deg,
                                              const int* __restrict__ csr_row,
                                              float* __restrict__ out) {
    const int t = threadIdx.x, lane = t & 63, w = t >> 6;
    const int i = blockIdx.x * 4 + w;
    const int s0 = start[i], dg = deg[i];
    const float hrv = hr2[i];
    const int c = (lane < 22) ? lane : 0;
    float acc = 0.f;
    for (int p = s0; p < s0 + dg; ++p) {
        const int r = csr_row[p];
        const float al = expf(hl2[r] + hrv) / z2[r];
        acc += al * h2[(size_t)r * 22 + c];
    }
    if (lane < 22) out[(size_t)i * 22 + lane] = acc;
}

extern "C" void kernel_launch(void* const* d_in, const int* in_sizes, int n_in,
                              void* d_out, int out_size, void* d_ws, size_t ws_size,
                              hipStream_t stream) {
    const float* x  = (const float*)d_in[0];
    const void*  ei = d_in[1];
    const float* W1 = (const float*)d_in[2];
    const float* a1 = (const float*)d_in[3];
    const float* W2 = (const float*)d_in[4];
    const float* a2 = (const float*)d_in[5];
    float* out = (float*)d_out;

    float* ws   = (float*)d_ws;
    float* h1   = ws;                  // N*512 = 5,120,000
    float* h1m  = ws + 5120000;        // N*128 = 1,280,000
    float* h2   = ws + 6400000;        // N*22  =   220,000
    float* hl1  = ws + 6620000;        // N*4
    float* hr1  = ws + 6660000;        // N*4
    float* z1   = ws + 6700000;        // N*4
    float* z2   = ws + 6740000;        // N
    float* hl2  = ws + 6750000;        // N
    float* hr2  = ws + 6760000;        // N
    int*   deg    = (int*)(ws + 6770000);  // N
    int*   start  = (int*)(ws + 6780000);  // N
    int*   cursor = (int*)(ws + 6790000);  // N
    int*   csr    = (int*)(ws + 6800000);  // E
    int*   flag   = (int*)(ws + 7120000);  // 1

    k_detect<<<1, 64, 0, stream>>>((const unsigned int*)ei, flag);
    // zero z1..z2..hl2/hr2..deg region (80,000 words starting at z1)
    k_zero<<<(80000 + 255) / 256, 256, 0, stream>>>(z1, 80000);
    k_gemm1<<<625, 256, 0, stream>>>(x, W1, h1);
    k_hlhr1<<<2500, 256, 0, stream>>>(h1, a1, hl1, hr1);
    k_edge1<<<1250, 256, 0, stream>>>(ei, flag, hl1, hr1, z1, deg);
    k_scan<<<1, 256, 0, stream>>>(deg, start, cursor);
    k_scatter<<<1250, 256, 0, stream>>>(ei, flag, cursor, csr);
    k_agg1<<<2500, 256, 0, stream>>>(h1, hl1, hr1, z1, start, deg, csr, h1m);
    k_gemm2<<<2500, 256, 0, stream>>>(h1m, W2, a2, h2, hl2, hr2);
    k_edge2<<<1250, 256, 0, stream>>>(ei, flag, hl2, hr2, z2);
    k_agg2<<<2500, 256, 0, stream>>>(h2, hl2, hr2, z2, start, deg, csr, out);
}

// Round 2
// 335.392 us; speedup vs baseline: 1.0191x; 1.0191x over previous
//
#include <hip/hip_runtime.h>

#define NN 10000
#define NE 320000

// ---------- edge index access (int32 vs int64 auto-detect) ----------
__device__ __forceinline__ int eread(const void* p, int is64, int i) {
    if (is64) return (int)((const long long*)p)[i];
    return ((const int*)p)[i];
}

__global__ void k_detect(const unsigned int* __restrict__ idx, int* __restrict__ flag) {
    if (threadIdx.x == 0 && blockIdx.x == 0) {
        int all0 = 1;
        for (int j = 1; j < 257; j += 2)
            if (idx[j] != 0u) { all0 = 0; break; }
        *flag = all0;  // 1 => int64 (high words all zero), 0 => int32
    }
}

__global__ void k_zero(float* __restrict__ p, int n) {
    int i = blockIdx.x * blockDim.x + threadIdx.x;
    if (i < n) p[i] = 0.0f;
}

__global__ void k_rcp(float* __restrict__ p, int n) {
    int i = blockIdx.x * blockDim.x + threadIdx.x;
    if (i < n) p[i] = 1.0f / p[i];
}

// ---------- fold W1 with a1: wlr[0..511]=wl (h*128+k), wlr[512..1023]=wr ----------
__global__ __launch_bounds__(256) void k_wprep(const float* __restrict__ W1,
                                               const float* __restrict__ a1,
                                               float* __restrict__ wlr) {
    const int g = blockIdx.x * 256 + threadIdx.x;  // 0..1023
    const int side = g >> 9, rem = g & 511;
    const int h = rem >> 7, k = rem & 127;
    const float* wrow = W1 + (size_t)k * 512 + h * 128;
    const float* av = a1 + h * 256 + side * 128;
    float s = 0.f;
    for (int d = 0; d < 128; d++) s += wrow[d] * av[d];
    wlr[side * 512 + h * 128 + k] = s;
}

// ---------- hl1/hr1 [N][4] directly from x (h1 never materialized) ----------
__global__ __launch_bounds__(256) void k_hlhr1(const float* __restrict__ x,
                                               const float* __restrict__ wlr,
                                               float* __restrict__ hl1, float* __restrict__ hr1) {
    __shared__ float ls[1024];
    const int t = threadIdx.x, lane = t & 63, w = t >> 6;
    ls[t] = wlr[t]; ls[t + 256] = wlr[t + 256];
    ls[t + 512] = wlr[t + 512]; ls[t + 768] = wlr[t + 768];
    __syncthreads();
    const int i = blockIdx.x * 4 + w;
    const float x0 = x[(size_t)i * 128 + lane];
    const float x1 = x[(size_t)i * 128 + 64 + lane];
    float v[8];
#pragma unroll
    for (int h = 0; h < 4; h++) {
        v[h]     = x0 * ls[h * 128 + lane]       + x1 * ls[h * 128 + 64 + lane];
        v[4 + h] = x0 * ls[512 + h * 128 + lane] + x1 * ls[512 + h * 128 + 64 + lane];
    }
#pragma unroll
    for (int off = 1; off < 64; off <<= 1) {
#pragma unroll
        for (int j = 0; j < 8; j++) v[j] += __shfl_xor(v[j], off);
    }
    if (lane == 0) {
        *(float4*)&hl1[i * 4] = make_float4(v[0], v[1], v[2], v[3]);
        *(float4*)&hr1[i * 4] = make_float4(v[4], v[5], v[6], v[7]);
    }
}

// ---------- edge pass 1: degree histogram (by col) + softmax denom z1 (by row) ----------
__global__ __launch_bounds__(256) void k_edge1(const void* __restrict__ ei, const int* __restrict__ flag,
                                               const float* __restrict__ hl1, const float* __restrict__ hr1,
                                               float* __restrict__ z1, int* __restrict__ deg) {
    const int is64 = *flag;
    const int e = blockIdx.x * blockDim.x + threadIdx.x;
    if (e >= NE) return;
    const int r = eread(ei, is64, e);
    const int c = eread(ei, is64, NE + e);
    atomicAdd(deg + c, 1);
    float4 l4 = *(const float4*)&hl1[r * 4];
    float4 r4 = *(const float4*)&hr1[c * 4];
    atomicAdd(&z1[r * 4 + 0], __expf(l4.x + r4.x));
    atomicAdd(&z1[r * 4 + 1], __expf(l4.y + r4.y));
    atomicAdd(&z1[r * 4 + 2], __expf(l4.z + r4.z));
    atomicAdd(&z1[r * 4 + 3], __expf(l4.w + r4.w));
}

// ---------- exclusive scan of deg -> start, cursor (single block) ----------
__global__ __launch_bounds__(256) void k_scan(const int* __restrict__ deg,
                                              int* __restrict__ start, int* __restrict__ cursor) {
    const int t = threadIdx.x;
    int loc[40];
    const int base = t * 40;
    int sum = 0;
#pragma unroll
    for (int j = 0; j < 40; j++) {
        int i = base + j;
        int v = (i < NN) ? deg[i] : 0;
        loc[j] = sum;
        sum += v;
    }
    const int lane = t & 63, w = t >> 6;
    int x = sum;
#pragma unroll
    for (int off = 1; off < 64; off <<= 1) {
        int y = __shfl_up(x, off);
        if (lane >= off) x += y;
    }
    __shared__ int ssum[4];
    if (lane == 63) ssum[w] = x;
    __syncthreads();
    int woff = 0;
#pragma unroll
    for (int k = 0; k < 4; k++)
        if (k < w) woff += ssum[k];
    const int excl = woff + x - sum;
#pragma unroll
    for (int j = 0; j < 40; j++) {
        int i = base + j;
        if (i < NN) {
            int v = excl + loc[j];
            start[i] = v;
            cursor[i] = v;
        }
    }
}

// ---------- scatter: CSR by col, payload = row index ----------
__global__ __launch_bounds__(256) void k_scatter(const void* __restrict__ ei, const int* __restrict__ flag,
                                                 int* __restrict__ cursor, int* __restrict__ csr_row) {
    const int is64 = *flag;
    const int e = blockIdx.x * blockDim.x + threadIdx.x;
    if (e >= NE) return;
    const int r = eread(ei, is64, e);
    const int c = eread(ei, is64, NE + e);
    const int pos = atomicAdd(cursor + c, 1);
    csr_row[pos] = r;
}

// ---------- L1 aggregation on x (128-wide): xagg[i][h][128] = sum alpha_h * x[row] ----------
__global__ __launch_bounds__(256) void k_agg1(const float* __restrict__ x,
                                              const float* __restrict__ hl1, const float* __restrict__ hr1,
                                              const float* __restrict__ rz1,
                                              const int* __restrict__ start, const int* __restrict__ deg,
                                              const int* __restrict__ csr_row,
                                              float* __restrict__ xagg) {
    const int t = threadIdx.x, lane = t & 63, w = t >> 6;
    const int i = blockIdx.x * 4 + w;
    const float4 hr4 = *(const float4*)&hr1[i * 4];
    const int s0 = start[i], dg = deg[i];
    float acc[8];
#pragma unroll
    for (int j = 0; j < 8; j++) acc[j] = 0.f;
    for (int p = s0; p < s0 + dg; ++p) {
        const int r = csr_row[p];
        const float4 hl4 = *(const float4*)&hl1[r * 4];
        const float4 rz4 = *(const float4*)&rz1[r * 4];
        const float a0 = __expf(hl4.x + hr4.x) * rz4.x;
        const float a1v = __expf(hl4.y + hr4.y) * rz4.y;
        const float a2v = __expf(hl4.z + hr4.z) * rz4.z;
        const float a3v = __expf(hl4.w + hr4.w) * rz4.w;
        const float2 xv = *(const float2*)&x[(size_t)r * 128 + lane * 2];
        acc[0] += a0 * xv.x;  acc[1] += a0 * xv.y;
        acc[2] += a1v * xv.x; acc[3] += a1v * xv.y;
        acc[4] += a2v * xv.x; acc[5] += a2v * xv.y;
        acc[6] += a3v * xv.x; acc[7] += a3v * xv.y;
    }
    float* op = xagg + (size_t)i * 512 + lane * 2;
#pragma unroll
    for (int h = 0; h < 4; h++)
        *(float2*)(op + h * 128) = make_float2(acc[h * 2], acc[h * 2 + 1]);
}

// ---------- fused GEMM: y[i,h,:] = xagg[i,h,:]@W1[:,h-block]; h1m = mean_h ELU(y) ----------
__global__ __launch_bounds__(256) void k_gemmF(const float* __restrict__ xagg,
                                               const float* __restrict__ W1,
                                               float* __restrict__ h1m) {
    __shared__ float xs[16 * 512];
    const int t = threadIdx.x;
    const int n0 = blockIdx.x * 16;
    {
        const float4* src = (const float4*)(xagg + (size_t)n0 * 512);
        float4* dst = (float4*)xs;
#pragma unroll
        for (int q = 0; q < 8; q++) dst[t + q * 256] = src[t + q * 256];
    }
    __syncthreads();
    const int j = t & 127, g = t >> 7;
    float hm[8];
#pragma unroll
    for (int n = 0; n < 8; n++) hm[n] = 0.f;
#pragma unroll
    for (int h = 0; h < 4; h++) {
        float acc[8];
#pragma unroll
        for (int n = 0; n < 8; n++) acc[n] = 0.f;
        const float* wp = W1 + h * 128 + j;
        for (int k = 0; k < 128; k += 4) {
            const float w0 = wp[(size_t)(k + 0) * 512];
            const float w1 = wp[(size_t)(k + 1) * 512];
            const float w2 = wp[(size_t)(k + 2) * 512];
            const float w3 = wp[(size_t)(k + 3) * 512];
#pragma unroll
            for (int n = 0; n < 8; n++) {
                const float4 xv = *(const float4*)&xs[(g * 8 + n) * 512 + h * 128 + k];
                acc[n] += xv.x * w0 + xv.y * w1 + xv.z * w2 + xv.w * w3;
            }
        }
#pragma unroll
        for (int n = 0; n < 8; n++) {
            const float v = acc[n];
            hm[n] += (v > 0.f) ? v : (__expf(v) - 1.f);  // ELU
        }
    }
#pragma unroll
    for (int n = 0; n < 8; n++)
        h1m[(size_t)(n0 + g * 8 + n) * 128 + j] = hm[n] * 0.25f;
}

// ---------- Layer-2 GEMM + attention terms ----------
__global__ __launch_bounds__(256) void k_gemm2(const float* __restrict__ h1m, const float* __restrict__ W2,
                                               const float* __restrict__ a2,
                                               float* __restrict__ h2, float* __restrict__ hl2,
                                               float* __restrict__ hr2) {
    __shared__ float sh[4][128];
    const int t = threadIdx.x, lane = t & 63, w = t >> 6;
    const int i = blockIdx.x * 4 + w;
    sh[w][lane]      = h1m[(size_t)i * 128 + lane];
    sh[w][lane + 64] = h1m[(size_t)i * 128 + 64 + lane];
    __syncthreads();
    float acc = 0.f;
    if (lane < 22) {
        for (int k = 0; k < 128; k++)
            acc += sh[w][k] * W2[k * 22 + lane];
        h2[(size_t)i * 22 + lane] = acc;
    }
    float pl = (lane < 22) ? acc * a2[lane] : 0.f;
    float pr = (lane < 22) ? acc * a2[22 + lane] : 0.f;
#pragma unroll
    for (int off = 1; off < 64; off <<= 1) {
        pl += __shfl_xor(pl, off);
        pr += __shfl_xor(pr, off);
    }
    if (lane == 0) {
        hl2[i] = pl;
        hr2[i] = pr;
    }
}

// ---------- edge pass 2: z2 denom ----------
__global__ __launch_bounds__(256) void k_edge2(const void* __restrict__ ei, const int* __restrict__ flag,
                                               const float* __restrict__ hl2, const float* __restrict__ hr2,
                                               float* __restrict__ z2) {
    const int is64 = *flag;
    const int e = blockIdx.x * blockDim.x + threadIdx.x;
    if (e >= NE) return;
    const int r = eread(ei, is64, e);
    const int c = eread(ei, is64, NE + e);
    atomicAdd(&z2[r], __expf(hl2[r] + hr2[c]));
}

// ---------- L2 aggregation -> output [N][22] ----------
__global__ __launch_bounds__(256) void k_agg2(const float* __restrict__ h2,
                                              const float* __restrict__ hl2, const float* __restrict__ hr2,
                                              const float* __restrict__ z2,
                                              const int* __restrict__ start, const int* __restrict__ deg,
                                              const int* __restrict__ csr_row,
                                              float* __restrict__ out) {
    const int t = threadIdx.x, lane = t & 63, w = t >> 6;
    const int i = blockIdx.x * 4 + w;
    const int s0 = start[i], dg = deg[i];
    const float hrv = hr2[i];
    const int c = (lane < 22) ? lane : 0;
    float acc = 0.f;
    for (int p = s0; p < s0 + dg; ++p) {
        const int r = csr_row[p];
        const float al = __expf(hl2[r] + hrv) / z2[r];
        acc += al * h2[(size_t)r * 22 + c];
    }
    if (lane < 22) out[(size_t)i * 22 + lane] = acc;
}

extern "C" void kernel_launch(void* const* d_in, const int* in_sizes, int n_in,
                              void* d_out, int out_size, void* d_ws, size_t ws_size,
                              hipStream_t stream) {
    const float* x  = (const float*)d_in[0];
    const void*  ei = d_in[1];
    const float* W1 = (const float*)d_in[2];
    const float* a1 = (const float*)d_in[3];
    const float* W2 = (const float*)d_in[4];
    const float* a2 = (const float*)d_in[5];
    float* out = (float*)d_out;

    float* ws   = (float*)d_ws;
    float* xagg = ws;                  // N*512 = 5,120,000
    float* h1m  = ws + 5120000;        // N*128 = 1,280,000
    float* h2   = ws + 6400000;        // N*22  =   220,000
    float* hl1  = ws + 6620000;        // N*4
    float* hr1  = ws + 6660000;        // N*4
    float* z1   = ws + 6700000;        // N*4 (becomes 1/z after k_rcp)
    float* z2   = ws + 6740000;        // N
    float* hl2  = ws + 6750000;        // N
    float* hr2  = ws + 6760000;        // N
    int*   deg    = (int*)(ws + 6770000);  // N
    int*   start  = (int*)(ws + 6780000);  // N
    int*   cursor = (int*)(ws + 6790000);  // N
    int*   csr    = (int*)(ws + 6800000);  // E -> ends 7,120,000
    int*   flag   = (int*)(ws + 7120000);  // 1 (+pad)
    float* wlr    = ws + 7120064;          // 1024

    k_detect<<<1, 64, 0, stream>>>((const unsigned int*)ei, flag);
    // zero z1(40k), z2(10k), hl2(10k), hr2(10k), deg(10k) = 80,000 words
    k_zero<<<(80000 + 255) / 256, 256, 0, stream>>>(z1, 80000);
    k_wprep<<<4, 256, 0, stream>>>(W1, a1, wlr);
    k_hlhr1<<<2500, 256, 0, stream>>>(x, wlr, hl1, hr1);
    k_edge1<<<1250, 256, 0, stream>>>(ei, flag, hl1, hr1, z1, deg);
    k_rcp<<<(40000 + 255) / 256, 256, 0, stream>>>(z1, 40000);
    k_scan<<<1, 256, 0, stream>>>(deg, start, cursor);
    k_scatter<<<1250, 256, 0, stream>>>(ei, flag, cursor, csr);
    k_agg1<<<2500, 256, 0, stream>>>(x, hl1, hr1, z1, start, deg, csr, xagg);
    k_gemmF<<<625, 256, 0, stream>>>(xagg, W1, h1m);
    k_gemm2<<<2500, 256, 0, stream>>>(h1m, W2, a2, h2, hl2, hr2);
    k_edge2<<<1250, 256, 0, stream>>>(ei, flag, hl2, hr2, z2);
    k_agg2<<<2500, 256, 0, stream>>>(h2, hl2, hr2, z2, start, deg, csr, out);
}

// Round 3
// 283.822 us; speedup vs baseline: 1.2043x; 1.1817x over previous
//
#include <hip/hip_runtime.h>

#define NN 10000
#define NE 320000

// ---------- edge index access (int32 vs int64 auto-detect) ----------
__device__ __forceinline__ int eread(const void* p, int is64, int i) {
    if (is64) return (int)((const long long*)p)[i];
    return ((const int*)p)[i];
}

__global__ void k_detect(const unsigned int* __restrict__ idx, int* __restrict__ flag) {
    if (threadIdx.x == 0 && blockIdx.x == 0) {
        int all0 = 1;
        for (int j = 1; j < 257; j += 2)
            if (idx[j] != 0u) { all0 = 0; break; }
        *flag = all0;  // 1 => int64 (high words all zero), 0 => int32
    }
}

__global__ void k_zeroi(int* __restrict__ p, int n) {
    int i = blockIdx.x * blockDim.x + threadIdx.x;
    if (i < n) p[i] = 0;
}

// ---------- fold W1 with a_r: wrf[h*128+k] = sum_d W1[k][h*128+d]*a1[h][128+d] ----------
__global__ __launch_bounds__(256) void k_wprep(const float* __restrict__ W1,
                                               const float* __restrict__ a1,
                                               float* __restrict__ wrf) {
    const int g = blockIdx.x * 256 + threadIdx.x;  // 0..511
    const int h = g >> 7, k = g & 127;
    const float* wrow = W1 + (size_t)k * 512 + h * 128;
    const float* av = a1 + h * 256 + 128;
    float s = 0.f;
    for (int d = 0; d < 128; d++) s += wrow[d] * av[d];
    wrf[h * 128 + k] = s;
}

// ---------- ehr1[i][4] = exp(x[i] . wrf[h]) ----------
__global__ __launch_bounds__(256) void k_hr1(const float* __restrict__ x,
                                             const float* __restrict__ wrf,
                                             float* __restrict__ ehr1) {
    __shared__ float ls[512];
    const int t = threadIdx.x, lane = t & 63, w = t >> 6;
    ls[t] = wrf[t];
    ls[t + 256] = wrf[t + 256];
    __syncthreads();
    const int i = blockIdx.x * 4 + w;
    const float x0 = x[(size_t)i * 128 + lane];
    const float x1 = x[(size_t)i * 128 + 64 + lane];
    float v[4];
#pragma unroll
    for (int h = 0; h < 4; h++)
        v[h] = x0 * ls[h * 128 + lane] + x1 * ls[h * 128 + 64 + lane];
#pragma unroll
    for (int off = 1; off < 64; off <<= 1) {
#pragma unroll
        for (int j = 0; j < 4; j++) v[j] += __shfl_xor(v[j], off);
    }
    if (lane == 0)
        *(float4*)&ehr1[i * 4] = make_float4(__expf(v[0]), __expf(v[1]), __expf(v[2]), __expf(v[3]));
}

// ---------- histograms: deg_c (by col) and deg_r (by row) ----------
__global__ __launch_bounds__(256) void k_hist(const void* __restrict__ ei, const int* __restrict__ flag,
                                              int* __restrict__ deg_c, int* __restrict__ deg_r) {
    const int is64 = *flag;
    const int e = blockIdx.x * blockDim.x + threadIdx.x;
    if (e >= NE) return;
    const int r = eread(ei, is64, e);
    const int c = eread(ei, is64, NE + e);
    atomicAdd(deg_c + c, 1);
    atomicAdd(deg_r + r, 1);
}

// ---------- single-block exclusive scan helper ----------
__device__ void scan_one(const int* __restrict__ deg, int* __restrict__ start,
                         int* __restrict__ cursor, int* ssum) {
    const int t = threadIdx.x;
    int loc[40];
    const int base = t * 40;
    int sum = 0;
#pragma unroll
    for (int j = 0; j < 40; j++) {
        int i = base + j;
        int v = (i < NN) ? deg[i] : 0;
        loc[j] = sum;
        sum += v;
    }
    const int lane = t & 63, w = t >> 6;
    int x = sum;
#pragma unroll
    for (int off = 1; off < 64; off <<= 1) {
        int y = __shfl_up(x, off);
        if (lane >= off) x += y;
    }
    __syncthreads();           // protect ssum reuse across invocations
    if (lane == 63) ssum[w] = x;
    __syncthreads();
    int woff = 0;
#pragma unroll
    for (int k = 0; k < 4; k++)
        if (k < w) woff += ssum[k];
    const int excl = woff + x - sum;
#pragma unroll
    for (int j = 0; j < 40; j++) {
        int i = base + j;
        if (i < NN) {
            int v = excl + loc[j];
            start[i] = v;
            cursor[i] = v;
        }
    }
}

__global__ __launch_bounds__(256) void k_scan2(const int* __restrict__ deg_c, const int* __restrict__ deg_r,
                                               int* __restrict__ start_c, int* __restrict__ cur_c,
                                               int* __restrict__ start_r, int* __restrict__ cur_r) {
    __shared__ int ssum[4];
    scan_one(deg_c, start_c, cur_c, ssum);
    scan_one(deg_r, start_r, cur_r, ssum);
}

// ---------- build dual CSR: csrA (by col, payload row), csrB (by row, payload col) ----------
__global__ __launch_bounds__(256) void k_build(const void* __restrict__ ei, const int* __restrict__ flag,
                                               int* __restrict__ cur_c, int* __restrict__ cur_r,
                                               int* __restrict__ csrA, int* __restrict__ csrB) {
    const int is64 = *flag;
    const int e = blockIdx.x * blockDim.x + threadIdx.x;
    if (e >= NE) return;
    const int r = eread(ei, is64, e);
    const int c = eread(ei, is64, NE + e);
    const int pa = atomicAdd(cur_c + c, 1);
    csrA[pa] = r;
    const int pb = atomicAdd(cur_r + r, 1);
    csrB[pb] = c;
}

// ---------- rz1[r][4] = 1 / sum_{e: row=r} ehr1[col_e][4] ----------
__global__ __launch_bounds__(256) void k_z1(const int* __restrict__ start_r, const int* __restrict__ deg_r,
                                            const int* __restrict__ csrB,
                                            const float* __restrict__ ehr1, float* __restrict__ rz1) {
    const int i = blockIdx.x * blockDim.x + threadIdx.x;
    if (i >= NN) return;
    const int s0 = start_r[i], d = deg_r[i];
    float zx = 0.f, zy = 0.f, zz = 0.f, zw = 0.f;
    for (int p = s0; p < s0 + d; ++p) {
        const int c = csrB[p];
        const float4 v = *(const float4*)&ehr1[c * 4];
        zx += v.x; zy += v.y; zz += v.z; zw += v.w;
    }
    *(float4*)&rz1[i * 4] = make_float4(1.f / zx, 1.f / zy, 1.f / zz, 1.f / zw);
}

// ---------- L1 aggregation on x: xagg[i][h][:] = ehr1[i][h] * sum rz1[r][h]*x[r][:] ----------
__global__ __launch_bounds__(256) void k_agg1(const float* __restrict__ x,
                                              const float* __restrict__ ehr1, const float* __restrict__ rz1,
                                              const int* __restrict__ start_c, const int* __restrict__ deg_c,
                                              const int* __restrict__ csrA,
                                              float* __restrict__ xagg) {
    const int t = threadIdx.x, lane = t & 63, w = t >> 6;
    const int i = blockIdx.x * 4 + w;
    const float4 er4 = *(const float4*)&ehr1[i * 4];
    const int s0 = start_c[i], dg = deg_c[i];
    float acc[8];
#pragma unroll
    for (int j = 0; j < 8; j++) acc[j] = 0.f;
    for (int p = s0; p < s0 + dg; ++p) {
        const int r = csrA[p];
        const float4 rz4 = *(const float4*)&rz1[r * 4];
        const float2 xv = *(const float2*)&x[(size_t)r * 128 + lane * 2];
        acc[0] += rz4.x * xv.x; acc[1] += rz4.x * xv.y;
        acc[2] += rz4.y * xv.x; acc[3] += rz4.y * xv.y;
        acc[4] += rz4.z * xv.x; acc[5] += rz4.z * xv.y;
        acc[6] += rz4.w * xv.x; acc[7] += rz4.w * xv.y;
    }
    acc[0] *= er4.x; acc[1] *= er4.x;
    acc[2] *= er4.y; acc[3] *= er4.y;
    acc[4] *= er4.z; acc[5] *= er4.z;
    acc[6] *= er4.w; acc[7] *= er4.w;
    float* op = xagg + (size_t)i * 512 + lane * 2;
#pragma unroll
    for (int h = 0; h < 4; h++)
        *(float2*)(op + h * 128) = make_float2(acc[h * 2], acc[h * 2 + 1]);
}

// ---------- fused GEMM: y[i,h,:] = xagg[i,h,:]@W1[:,h-block]; h1m = mean_h ELU(y) ----------
__global__ __launch_bounds__(256) void k_gemmF(const float* __restrict__ xagg,
                                               const float* __restrict__ W1,
                                               float* __restrict__ h1m) {
    __shared__ float xs[16 * 512];
    const int t = threadIdx.x;
    const int n0 = blockIdx.x * 16;
    {
        const float4* src = (const float4*)(xagg + (size_t)n0 * 512);
        float4* dst = (float4*)xs;
#pragma unroll
        for (int q = 0; q < 8; q++) dst[t + q * 256] = src[t + q * 256];
    }
    __syncthreads();
    const int j = t & 127, g = t >> 7;
    float hm[8];
#pragma unroll
    for (int n = 0; n < 8; n++) hm[n] = 0.f;
#pragma unroll
    for (int h = 0; h < 4; h++) {
        float acc[8];
#pragma unroll
        for (int n = 0; n < 8; n++) acc[n] = 0.f;
        const float* wp = W1 + h * 128 + j;
        for (int k = 0; k < 128; k += 4) {
            const float w0 = wp[(size_t)(k + 0) * 512];
            const float w1 = wp[(size_t)(k + 1) * 512];
            const float w2 = wp[(size_t)(k + 2) * 512];
            const float w3 = wp[(size_t)(k + 3) * 512];
#pragma unroll
            for (int n = 0; n < 8; n++) {
                const float4 xv = *(const float4*)&xs[(g * 8 + n) * 512 + h * 128 + k];
                acc[n] += xv.x * w0 + xv.y * w1 + xv.z * w2 + xv.w * w3;
            }
        }
#pragma unroll
        for (int n = 0; n < 8; n++) {
            const float v = acc[n];
            hm[n] += (v > 0.f) ? v : (__expf(v) - 1.f);  // ELU
        }
    }
#pragma unroll
    for (int n = 0; n < 8; n++)
        h1m[(size_t)(n0 + g * 8 + n) * 128 + j] = hm[n] * 0.25f;
}

// ---------- Layer-2 GEMM + exp(hr2) ----------
__global__ __launch_bounds__(256) void k_gemm2(const float* __restrict__ h1m, const float* __restrict__ W2,
                                               const float* __restrict__ a2,
                                               float* __restrict__ h2, float* __restrict__ ehr2) {
    __shared__ float sh[4][128];
    const int t = threadIdx.x, lane = t & 63, w = t >> 6;
    const int i = blockIdx.x * 4 + w;
    sh[w][lane]      = h1m[(size_t)i * 128 + lane];
    sh[w][lane + 64] = h1m[(size_t)i * 128 + 64 + lane];
    __syncthreads();
    float acc = 0.f;
    if (lane < 22) {
        for (int k = 0; k < 128; k++)
            acc += sh[w][k] * W2[k * 22 + lane];
        h2[(size_t)i * 22 + lane] = acc;
    }
    float pr = (lane < 22) ? acc * a2[22 + lane] : 0.f;
#pragma unroll
    for (int off = 1; off < 64; off <<= 1)
        pr += __shfl_xor(pr, off);
    if (lane == 0) ehr2[i] = __expf(pr);
}

// ---------- rz2[r] = 1 / sum_{e: row=r} ehr2[col_e] ----------
__global__ __launch_bounds__(256) void k_z2(const int* __restrict__ start_r, const int* __restrict__ deg_r,
                                            const int* __restrict__ csrB,
                                            const float* __restrict__ ehr2, float* __restrict__ rz2) {
    const int i = blockIdx.x * blockDim.x + threadIdx.x;
    if (i >= NN) return;
    const int s0 = start_r[i], d = deg_r[i];
    float z = 0.f;
    for (int p = s0; p < s0 + d; ++p)
        z += ehr2[csrB[p]];
    rz2[i] = 1.f / z;
}

// ---------- L2 aggregation -> output [N][22] ----------
__global__ __launch_bounds__(256) void k_agg2(const float* __restrict__ h2,
                                              const float* __restrict__ ehr2, const float* __restrict__ rz2,
                                              const int* __restrict__ start_c, const int* __restrict__ deg_c,
                                              const int* __restrict__ csrA,
                                              float* __restrict__ out) {
    const int t = threadIdx.x, lane = t & 63, w = t >> 6;
    const int i = blockIdx.x * 4 + w;
    const int s0 = start_c[i], dg = deg_c[i];
    const float e2 = ehr2[i];
    const int c = (lane < 22) ? lane : 0;
    float acc = 0.f;
    for (int p = s0; p < s0 + dg; ++p) {
        const int r = csrA[p];
        acc += rz2[r] * h2[(size_t)r * 22 + c];
    }
    if (lane < 22) out[(size_t)i * 22 + lane] = acc * e2;
}

extern "C" void kernel_launch(void* const* d_in, const int* in_sizes, int n_in,
                              void* d_out, int out_size, void* d_ws, size_t ws_size,
                              hipStream_t stream) {
    const float* x  = (const float*)d_in[0];
    const void*  ei = d_in[1];
    const float* W1 = (const float*)d_in[2];
    const float* a1 = (const float*)d_in[3];
    const float* W2 = (const float*)d_in[4];
    const float* a2 = (const float*)d_in[5];
    float* out = (float*)d_out;

    float* ws   = (float*)d_ws;
    float* xagg = ws;                        // 5,120,000
    float* h1m  = ws + 5120000;              // 1,280,000
    float* h2   = ws + 6400000;              //   220,000
    float* ehr1 = ws + 6620000;              //    40,000
    float* rz1  = ws + 6660000;              //    40,000
    float* ehr2 = ws + 6700000;              //    10,000
    float* rz2  = ws + 6710000;              //    10,000
    int* deg_c   = (int*)(ws + 6720000);     //    10,000
    int* deg_r   = (int*)(ws + 6730000);
    int* start_c = (int*)(ws + 6740000);
    int* start_r = (int*)(ws + 6750000);
    int* cur_c   = (int*)(ws + 6760000);
    int* cur_r   = (int*)(ws + 6770000);
    int* csrA    = (int*)(ws + 6780000);     //   320,000
    int* csrB    = (int*)(ws + 7100000);     //   320,000
    int* flag    = (int*)(ws + 7420000);
    float* wrf   = ws + 7420064;             //       512

    k_detect<<<1, 64, 0, stream>>>((const unsigned int*)ei, flag);
    k_zeroi<<<(20000 + 255) / 256, 256, 0, stream>>>(deg_c, 20000);   // deg_c + deg_r
    k_wprep<<<2, 256, 0, stream>>>(W1, a1, wrf);
    k_hr1<<<2500, 256, 0, stream>>>(x, wrf, ehr1);
    k_hist<<<1250, 256, 0, stream>>>(ei, flag, deg_c, deg_r);
    k_scan2<<<1, 256, 0, stream>>>(deg_c, deg_r, start_c, cur_c, start_r, cur_r);
    k_build<<<1250, 256, 0, stream>>>(ei, flag, cur_c, cur_r, csrA, csrB);
    k_z1<<<(NN + 255) / 256, 256, 0, stream>>>(start_r, deg_r, csrB, ehr1, rz1);
    k_agg1<<<2500, 256, 0, stream>>>(x, ehr1, rz1, start_c, deg_c, csrA, xagg);
    k_gemmF<<<625, 256, 0, stream>>>(xagg, W1, h1m);
    k_gemm2<<<2500, 256, 0, stream>>>(h1m, W2, a2, h2, ehr2);
    k_z2<<<(NN + 255) / 256, 256, 0, stream>>>(start_r, deg_r, csrB, ehr2, rz2);
    k_agg2<<<2500, 256, 0, stream>>>(h2, ehr2, rz2, start_c, deg_c, csrA, out);
}

// Round 4
// 246.684 us; speedup vs baseline: 1.3856x; 1.1505x over previous
//
#include <hip/hip_runtime.h>

#define NN 10000
#define NE 320000

typedef short short8 __attribute__((ext_vector_type(8)));
typedef float f32x4 __attribute__((ext_vector_type(4)));

__device__ __forceinline__ unsigned short f2bf(float f) {
    unsigned u = __float_as_uint(f);
    return (unsigned short)((u + 0x7FFFu + ((u >> 16) & 1u)) >> 16);  // RNE
}

// ---------- edge index access (int32 vs int64 auto-detect) ----------
__device__ __forceinline__ int eread(const void* p, int is64, int i) {
    if (is64) return (int)((const long long*)p)[i];
    return ((const int*)p)[i];
}

__global__ void k_detect(const unsigned int* __restrict__ idx, int* __restrict__ flag) {
    if (threadIdx.x == 0 && blockIdx.x == 0) {
        int all0 = 1;
        for (int j = 1; j < 257; j += 2)
            if (idx[j] != 0u) { all0 = 0; break; }
        *flag = all0;  // 1 => int64 (high words all zero), 0 => int32
    }
}

__global__ void k_zeroi(int* __restrict__ p, int n) {
    int i = blockIdx.x * blockDim.x + threadIdx.x;
    if (i < n) p[i] = 0;
}

// ---------- fold W1 with a_r: wrf[h*128+k] = sum_d W1[k][h*128+d]*a1[h][128+d] ----------
__global__ __launch_bounds__(256) void k_wprep(const float* __restrict__ W1,
                                               const float* __restrict__ a1,
                                               float* __restrict__ wrf) {
    const int g = blockIdx.x * 256 + threadIdx.x;  // 0..511
    const int h = g >> 7, k = g & 127;
    const float* wrow = W1 + (size_t)k * 512 + h * 128;
    const float* av = a1 + h * 256 + 128;
    float s = 0.f;
    for (int d = 0; d < 128; d++) s += wrow[d] * av[d];
    wrf[h * 128 + k] = s;
}

// ---------- W1t[h][j][k] = bf16(W1[k][h*128+j]) ----------
__global__ __launch_bounds__(256) void k_w1t(const float* __restrict__ W1,
                                             unsigned short* __restrict__ W1t) {
    const int g = blockIdx.x * 256 + threadIdx.x;  // 0..65535
    const int h = g >> 14, j = (g >> 7) & 127, k = g & 127;
    W1t[g] = f2bf(W1[(size_t)k * 512 + h * 128 + j]);
}

// ---------- ehr1[i][4] = exp(x[i] . wrf[h]) ----------
__global__ __launch_bounds__(256) void k_hr1(const float* __restrict__ x,
                                             const float* __restrict__ wrf,
                                             float* __restrict__ ehr1) {
    __shared__ float ls[512];
    const int t = threadIdx.x, lane = t & 63, w = t >> 6;
    ls[t] = wrf[t];
    ls[t + 256] = wrf[t + 256];
    __syncthreads();
    const int i = blockIdx.x * 4 + w;
    const float x0 = x[(size_t)i * 128 + lane];
    const float x1 = x[(size_t)i * 128 + 64 + lane];
    float v[4];
#pragma unroll
    for (int h = 0; h < 4; h++)
        v[h] = x0 * ls[h * 128 + lane] + x1 * ls[h * 128 + 64 + lane];
#pragma unroll
    for (int off = 1; off < 64; off <<= 1) {
#pragma unroll
        for (int j = 0; j < 4; j++) v[j] += __shfl_xor(v[j], off);
    }
    if (lane == 0)
        *(float4*)&ehr1[i * 4] = make_float4(__expf(v[0]), __expf(v[1]), __expf(v[2]), __expf(v[3]));
}

// ---------- histograms: deg_c (by col) and deg_r (by row) ----------
__global__ __launch_bounds__(256) void k_hist(const void* __restrict__ ei, const int* __restrict__ flag,
                                              int* __restrict__ deg_c, int* __restrict__ deg_r) {
    const int is64 = *flag;
    const int e = blockIdx.x * blockDim.x + threadIdx.x;
    if (e >= NE) return;
    const int r = eread(ei, is64, e);
    const int c = eread(ei, is64, NE + e);
    atomicAdd(deg_c + c, 1);
    atomicAdd(deg_r + r, 1);
}

// ---------- single-block exclusive scan helper ----------
__device__ void scan_one(const int* __restrict__ deg, int* __restrict__ start,
                         int* __restrict__ cursor, int* ssum) {
    const int t = threadIdx.x;
    int loc[40];
    const int base = t * 40;
    int sum = 0;
#pragma unroll
    for (int j = 0; j < 40; j++) {
        int i = base + j;
        int v = (i < NN) ? deg[i] : 0;
        loc[j] = sum;
        sum += v;
    }
    const int lane = t & 63, w = t >> 6;
    int x = sum;
#pragma unroll
    for (int off = 1; off < 64; off <<= 1) {
        int y = __shfl_up(x, off);
        if (lane >= off) x += y;
    }
    __syncthreads();
    if (lane == 63) ssum[w] = x;
    __syncthreads();
    int woff = 0;
#pragma unroll
    for (int k = 0; k < 4; k++)
        if (k < w) woff += ssum[k];
    const int excl = woff + x - sum;
#pragma unroll
    for (int j = 0; j < 40; j++) {
        int i = base + j;
        if (i < NN) {
            int v = excl + loc[j];
            start[i] = v;
            cursor[i] = v;
        }
    }
}

__global__ __launch_bounds__(256) void k_scan2(const int* __restrict__ deg_c, const int* __restrict__ deg_r,
                                               int* __restrict__ start_c, int* __restrict__ cur_c,
                                               int* __restrict__ start_r, int* __restrict__ cur_r) {
    __shared__ int ssum[4];
    scan_one(deg_c, start_c, cur_c, ssum);
    scan_one(deg_r, start_r, cur_r, ssum);
}

// ---------- build dual CSR: csrA (by col, payload row), csrB (by row, payload col) ----------
__global__ __launch_bounds__(256) void k_build(const void* __restrict__ ei, const int* __restrict__ flag,
                                               int* __restrict__ cur_c, int* __restrict__ cur_r,
                                               int* __restrict__ csrA, int* __restrict__ csrB) {
    const int is64 = *flag;
    const int e = blockIdx.x * blockDim.x + threadIdx.x;
    if (e >= NE) return;
    const int r = eread(ei, is64, e);
    const int c = eread(ei, is64, NE + e);
    const int pa = atomicAdd(cur_c + c, 1);
    csrA[pa] = r;
    const int pb = atomicAdd(cur_r + r, 1);
    csrB[pb] = c;
}

// ---------- rz1[r][4] = 1 / sum_{e: row=r} ehr1[col_e][4] ----------
__global__ __launch_bounds__(256) void k_z1(const int* __restrict__ start_r, const int* __restrict__ deg_r,
                                            const int* __restrict__ csrB,
                                            const float* __restrict__ ehr1, float* __restrict__ rz1) {
    const int i = blockIdx.x * blockDim.x + threadIdx.x;
    if (i >= NN) return;
    const int s0 = start_r[i], d = deg_r[i];
    float zx = 0.f, zy = 0.f, zz = 0.f, zw = 0.f;
    for (int p = s0; p < s0 + d; ++p) {
        const int c = csrB[p];
        const float4 v = *(const float4*)&ehr1[c * 4];
        zx += v.x; zy += v.y; zz += v.z; zw += v.w;
    }
    *(float4*)&rz1[i * 4] = make_float4(1.f / zx, 1.f / zy, 1.f / zz, 1.f / zw);
}

// ---------- L1 aggregation on x -> xaggb (bf16, [i][h][128]) ----------
__global__ __launch_bounds__(256) void k_agg1(const float* __restrict__ x,
                                              const float* __restrict__ ehr1, const float* __restrict__ rz1,
                                              const int* __restrict__ start_c, const int* __restrict__ deg_c,
                                              const int* __restrict__ csrA,
                                              unsigned short* __restrict__ xaggb) {
    const int t = threadIdx.x, lane = t & 63, w = t >> 6;
    const int i = blockIdx.x * 4 + w;
    const float4 er4 = *(const float4*)&ehr1[i * 4];
    const int s0 = start_c[i], dg = deg_c[i];
    float acc[8];
#pragma unroll
    for (int j = 0; j < 8; j++) acc[j] = 0.f;
    for (int p = s0; p < s0 + dg; ++p) {
        const int r = csrA[p];
        const float4 rz4 = *(const float4*)&rz1[r * 4];
        const float2 xv = *(const float2*)&x[(size_t)r * 128 + lane * 2];
        acc[0] += rz4.x * xv.x; acc[1] += rz4.x * xv.y;
        acc[2] += rz4.y * xv.x; acc[3] += rz4.y * xv.y;
        acc[4] += rz4.z * xv.x; acc[5] += rz4.z * xv.y;
        acc[6] += rz4.w * xv.x; acc[7] += rz4.w * xv.y;
    }
    const float ef[4] = {er4.x, er4.y, er4.z, er4.w};
    unsigned short* op = xaggb + (size_t)i * 512 + lane * 2;
#pragma unroll
    for (int h = 0; h < 4; h++) {
        ushort2 st;
        st.x = f2bf(acc[h * 2] * ef[h]);
        st.y = f2bf(acc[h * 2 + 1] * ef[h]);
        *(ushort2*)(op + h * 128) = st;
    }
}

// ---------- MFMA GEMM: y[i,h,:] = xaggb[i,h,:]@W1h; h1m = mean_h ELU(y) ----------
__global__ __launch_bounds__(256) void k_gemmF(const unsigned short* __restrict__ xaggb,
                                               const unsigned short* __restrict__ W1t,
                                               float* __restrict__ h1m) {
    const int t = threadIdx.x, lane = t & 63, w = t >> 6;
    const int n0 = blockIdx.x * 32;          // 32-node tile
    const int r16 = lane & 15, grp = lane >> 4;
    const int jbase = w * 32;                // wave's 32-col slice
    f32x4 hm[2][2];
#pragma unroll
    for (int m = 0; m < 2; m++)
#pragma unroll
        for (int n = 0; n < 2; n++) hm[m][n] = (f32x4)0.f;

#pragma unroll
    for (int h = 0; h < 4; h++) {
        f32x4 acc[2][2];
#pragma unroll
        for (int m = 0; m < 2; m++)
#pragma unroll
            for (int n = 0; n < 2; n++) acc[m][n] = (f32x4)0.f;
#pragma unroll
        for (int kk = 0; kk < 128; kk += 32) {
            const int k0 = kk + grp * 8;
            short8 a0 = *(const short8*)&xaggb[((size_t)(n0 + r16) * 4 + h) * 128 + k0];
            short8 a1 = *(const short8*)&xaggb[((size_t)(n0 + 16 + r16) * 4 + h) * 128 + k0];
            short8 b0 = *(const short8*)&W1t[(size_t)h * 16384 + (jbase + r16) * 128 + k0];
            short8 b1 = *(const short8*)&W1t[(size_t)h * 16384 + (jbase + 16 + r16) * 128 + k0];
            acc[0][0] = __builtin_amdgcn_mfma_f32_16x16x32_bf16(a0, b0, acc[0][0], 0, 0, 0);
            acc[1][0] = __builtin_amdgcn_mfma_f32_16x16x32_bf16(a1, b0, acc[1][0], 0, 0, 0);
            acc[0][1] = __builtin_amdgcn_mfma_f32_16x16x32_bf16(a0, b1, acc[0][1], 0, 0, 0);
            acc[1][1] = __builtin_amdgcn_mfma_f32_16x16x32_bf16(a1, b1, acc[1][1], 0, 0, 0);
        }
#pragma unroll
        for (int m = 0; m < 2; m++)
#pragma unroll
            for (int n = 0; n < 2; n++)
#pragma unroll
                for (int r = 0; r < 4; r++) {
                    const float v = acc[m][n][r];
                    hm[m][n][r] += (v > 0.f) ? v : (__expf(v) - 1.f);  // ELU
                }
    }
    // C/D layout: col = lane&15, row = grp*4 + r  [m89-verified]
#pragma unroll
    for (int m = 0; m < 2; m++)
#pragma unroll
        for (int n = 0; n < 2; n++)
#pragma unroll
            for (int r = 0; r < 4; r++) {
                const int node = n0 + m * 16 + grp * 4 + r;  // pad rows ok (alloc +16)
                const int col = jbase + n * 16 + r16;
                h1m[(size_t)node * 128 + col] = 0.25f * hm[m][n][r];
            }
}

// ---------- Layer-2 GEMM + exp(hr2) ----------
__global__ __launch_bounds__(256) void k_gemm2(const float* __restrict__ h1m, const float* __restrict__ W2,
                                               const float* __restrict__ a2,
                                               float* __restrict__ h2, float* __restrict__ ehr2) {
    __shared__ float sh[4][128];
    const int t = threadIdx.x, lane = t & 63, w = t >> 6;
    const int i = blockIdx.x * 4 + w;
    sh[w][lane]      = h1m[(size_t)i * 128 + lane];
    sh[w][lane + 64] = h1m[(size_t)i * 128 + 64 + lane];
    __syncthreads();
    float acc = 0.f;
    if (lane < 22) {
        for (int k = 0; k < 128; k++)
            acc += sh[w][k] * W2[k * 22 + lane];
        h2[(size_t)i * 22 + lane] = acc;
    }
    float pr = (lane < 22) ? acc * a2[22 + lane] : 0.f;
#pragma unroll
    for (int off = 1; off < 64; off <<= 1)
        pr += __shfl_xor(pr, off);
    if (lane == 0) ehr2[i] = __expf(pr);
}

// ---------- rz2[r] = 1 / sum_{e: row=r} ehr2[col_e] ----------
__global__ __launch_bounds__(256) void k_z2(const int* __restrict__ start_r, const int* __restrict__ deg_r,
                                            const int* __restrict__ csrB,
                                            const float* __restrict__ ehr2, float* __restrict__ rz2) {
    const int i = blockIdx.x * blockDim.x + threadIdx.x;
    if (i >= NN) return;
    const int s0 = start_r[i], d = deg_r[i];
    float z = 0.f;
    for (int p = s0; p < s0 + d; ++p)
        z += ehr2[csrB[p]];
    rz2[i] = 1.f / z;
}

// ---------- L2 aggregation -> output [N][22] ----------
__global__ __launch_bounds__(256) void k_agg2(const float* __restrict__ h2,
                                              const float* __restrict__ ehr2, const float* __restrict__ rz2,
                                              const int* __restrict__ start_c, const int* __restrict__ deg_c,
                                              const int* __restrict__ csrA,
                                              float* __restrict__ out) {
    const int t = threadIdx.x, lane = t & 63, w = t >> 6;
    const int i = blockIdx.x * 4 + w;
    const int s0 = start_c[i], dg = deg_c[i];
    const float e2 = ehr2[i];
    const int c = (lane < 22) ? lane : 0;
    float acc = 0.f;
    for (int p = s0; p < s0 + dg; ++p) {
        const int r = csrA[p];
        acc += rz2[r] * h2[(size_t)r * 22 + c];
    }
    if (lane < 22) out[(size_t)i * 22 + lane] = acc * e2;
}

extern "C" void kernel_launch(void* const* d_in, const int* in_sizes, int n_in,
                              void* d_out, int out_size, void* d_ws, size_t ws_size,
                              hipStream_t stream) {
    const float* x  = (const float*)d_in[0];
    const void*  ei = d_in[1];
    const float* W1 = (const float*)d_in[2];
    const float* a1 = (const float*)d_in[3];
    const float* W2 = (const float*)d_in[4];
    const float* a2 = (const float*)d_in[5];
    float* out = (float*)d_out;

    float* ws = (float*)d_ws;
    unsigned short* xaggb = (unsigned short*)ws;      // 10016*512 ushorts (pad rows 10000..10015)
    float* h1m  = ws + 2600000;                       // 10016*128 = 1,282,048 (padded)
    float* h2   = ws + 3890000;                       //   220,000
    float* ehr1 = ws + 4110000;                       //    40,000
    float* rz1  = ws + 4150000;                       //    40,000
    float* ehr2 = ws + 4190000;                       //    10,000
    float* rz2  = ws + 4200000;                       //    10,000
    int* deg_c   = (int*)(ws + 4210000);
    int* deg_r   = (int*)(ws + 4220000);
    int* start_c = (int*)(ws + 4230000);
    int* start_r = (int*)(ws + 4240000);
    int* cur_c   = (int*)(ws + 4250000);
    int* cur_r   = (int*)(ws + 4260000);
    int* csrA    = (int*)(ws + 4270000);              //   320,000
    int* csrB    = (int*)(ws + 4590000);              //   320,000
    int* flag    = (int*)(ws + 4910000);
    float* wrf   = ws + 4910064;                      //       512
    unsigned short* W1t = (unsigned short*)(ws + 4911000);  // 65,536 ushorts

    k_detect<<<1, 64, 0, stream>>>((const unsigned int*)ei, flag);
    k_zeroi<<<(20000 + 255) / 256, 256, 0, stream>>>(deg_c, 20000);   // deg_c + deg_r
    k_wprep<<<2, 256, 0, stream>>>(W1, a1, wrf);
    k_w1t<<<256, 256, 0, stream>>>(W1, W1t);
    k_hr1<<<2500, 256, 0, stream>>>(x, wrf, ehr1);
    k_hist<<<1250, 256, 0, stream>>>(ei, flag, deg_c, deg_r);
    k_scan2<<<1, 256, 0, stream>>>(deg_c, deg_r, start_c, cur_c, start_r, cur_r);
    k_build<<<1250, 256, 0, stream>>>(ei, flag, cur_c, cur_r, csrA, csrB);
    k_z1<<<(NN + 255) / 256, 256, 0, stream>>>(start_r, deg_r, csrB, ehr1, rz1);
    k_agg1<<<2500, 256, 0, stream>>>(x, ehr1, rz1, start_c, deg_c, csrA, xaggb);
    k_gemmF<<<313, 256, 0, stream>>>(xaggb, W1t, h1m);
    k_gemm2<<<2500, 256, 0, stream>>>(h1m, W2, a2, h2, ehr2);
    k_z2<<<(NN + 255) / 256, 256, 0, stream>>>(start_r, deg_r, csrB, ehr2, rz2);
    k_agg2<<<2500, 256, 0, stream>>>(h2, ehr2, rz2, start_c, deg_c, csrA, out);
}

// Round 5
// 187.754 us; speedup vs baseline: 1.8205x; 1.3139x over previous
//
#include <hip/hip_runtime.h>

#define NN 10000
#define NE 320000

typedef short short8 __attribute__((ext_vector_type(8)));
typedef float f32x4 __attribute__((ext_vector_type(4)));

__device__ __forceinline__ unsigned short f2bf(float f) {
    unsigned u = __float_as_uint(f);
    return (unsigned short)((u + 0x7FFFu + ((u >> 16) & 1u)) >> 16);  // RNE
}
__device__ __forceinline__ float bflo(unsigned v) { return __uint_as_float(v << 16); }
__device__ __forceinline__ float bfhi(unsigned v) { return __uint_as_float(v & 0xffff0000u); }

// ---------- edge index access (int32 vs int64 auto-detect) ----------
__device__ __forceinline__ int eread(const void* p, int is64, int i) {
    if (is64) return (int)((const long long*)p)[i];
    return ((const int*)p)[i];
}

__global__ void k_detect(const unsigned int* __restrict__ idx, int* __restrict__ flag) {
    if (threadIdx.x == 0 && blockIdx.x == 0) {
        int all0 = 1;
        for (int j = 1; j < 257; j += 2)
            if (idx[j] != 0u) { all0 = 0; break; }
        *flag = all0;  // 1 => int64 (high words all zero), 0 => int32
    }
}

__global__ void k_zeroi(int* __restrict__ p, int n) {
    int i = blockIdx.x * blockDim.x + threadIdx.x;
    if (i < n) p[i] = 0;
}

// ---------- xb = bf16(x) : 2.56 MB, L2-resident gather target ----------
__global__ __launch_bounds__(256) void k_xb(const float* __restrict__ x,
                                            unsigned short* __restrict__ xb) {
    const int g = blockIdx.x * 256 + threadIdx.x;  // 640,000 pairs
    const float2 v = *(const float2*)&x[(size_t)g * 2];
    ushort2 o; o.x = f2bf(v.x); o.y = f2bf(v.y);
    *(ushort2*)&xb[(size_t)g * 2] = o;
}

// ---------- fold W1 with a_r: wrf[h*128+k] = sum_d W1[k][h*128+d]*a1[h][128+d] ----------
__global__ __launch_bounds__(256) void k_wprep(const float* __restrict__ W1,
                                               const float* __restrict__ a1,
                                               float* __restrict__ wrf) {
    const int g = blockIdx.x * 256 + threadIdx.x;  // 0..511
    const int h = g >> 7, k = g & 127;
    const float* wrow = W1 + (size_t)k * 512 + h * 128;
    const float* av = a1 + h * 256 + 128;
    float s = 0.f;
    for (int d = 0; d < 128; d++) s += wrow[d] * av[d];
    wrf[h * 128 + k] = s;
}

// ---------- W1t[h][j][k] = bf16(W1[k][h*128+j]) ----------
__global__ __launch_bounds__(256) void k_w1t(const float* __restrict__ W1,
                                             unsigned short* __restrict__ W1t) {
    const int g = blockIdx.x * 256 + threadIdx.x;  // 0..65535
    const int h = g >> 14, j = (g >> 7) & 127, k = g & 127;
    W1t[g] = f2bf(W1[(size_t)k * 512 + h * 128 + j]);
}

// ---------- ehr1[i][4] = exp(x[i] . wrf[h]) ----------
__global__ __launch_bounds__(256) void k_hr1(const float* __restrict__ x,
                                             const float* __restrict__ wrf,
                                             float* __restrict__ ehr1) {
    __shared__ float ls[512];
    const int t = threadIdx.x, lane = t & 63, w = t >> 6;
    ls[t] = wrf[t];
    ls[t + 256] = wrf[t + 256];
    __syncthreads();
    const int i = blockIdx.x * 4 + w;
    const float x0 = x[(size_t)i * 128 + lane];
    const float x1 = x[(size_t)i * 128 + 64 + lane];
    float v[4];
#pragma unroll
    for (int h = 0; h < 4; h++)
        v[h] = x0 * ls[h * 128 + lane] + x1 * ls[h * 128 + 64 + lane];
#pragma unroll
    for (int off = 1; off < 64; off <<= 1) {
#pragma unroll
        for (int j = 0; j < 4; j++) v[j] += __shfl_xor(v[j], off);
    }
    if (lane == 0)
        *(float4*)&ehr1[i * 4] = make_float4(__expf(v[0]), __expf(v[1]), __expf(v[2]), __expf(v[3]));
}

// ---------- histograms: deg_c (by col) and deg_r (by row) ----------
__global__ __launch_bounds__(256) void k_hist(const void* __restrict__ ei, const int* __restrict__ flag,
                                              int* __restrict__ deg_c, int* __restrict__ deg_r) {
    const int is64 = *flag;
    const int e = blockIdx.x * blockDim.x + threadIdx.x;
    if (e >= NE) return;
    const int r = eread(ei, is64, e);
    const int c = eread(ei, is64, NE + e);
    atomicAdd(deg_c + c, 1);
    atomicAdd(deg_r + r, 1);
}

// ---------- single-block exclusive scan helper ----------
__device__ void scan_one(const int* __restrict__ deg, int* __restrict__ start,
                         int* __restrict__ cursor, int* ssum) {
    const int t = threadIdx.x;
    int loc[40];
    const int base = t * 40;
    int sum = 0;
#pragma unroll
    for (int j = 0; j < 40; j++) {
        int i = base + j;
        int v = (i < NN) ? deg[i] : 0;
        loc[j] = sum;
        sum += v;
    }
    const int lane = t & 63, w = t >> 6;
    int x = sum;
#pragma unroll
    for (int off = 1; off < 64; off <<= 1) {
        int y = __shfl_up(x, off);
        if (lane >= off) x += y;
    }
    __syncthreads();
    if (lane == 63) ssum[w] = x;
    __syncthreads();
    int woff = 0;
#pragma unroll
    for (int k = 0; k < 4; k++)
        if (k < w) woff += ssum[k];
    const int excl = woff + x - sum;
#pragma unroll
    for (int j = 0; j < 40; j++) {
        int i = base + j;
        if (i < NN) {
            int v = excl + loc[j];
            start[i] = v;
            cursor[i] = v;
        }
    }
}

__global__ __launch_bounds__(256) void k_scan2(const int* __restrict__ deg_c, const int* __restrict__ deg_r,
                                               int* __restrict__ start_c, int* __restrict__ cur_c,
                                               int* __restrict__ start_r, int* __restrict__ cur_r) {
    __shared__ int ssum[4];
    scan_one(deg_c, start_c, cur_c, ssum);
    scan_one(deg_r, start_r, cur_r, ssum);
}

// ---------- build dual CSR: csrA (by col, payload row), csrB (by row, payload col) ----------
__global__ __launch_bounds__(256) void k_build(const void* __restrict__ ei, const int* __restrict__ flag,
                                               int* __restrict__ cur_c, int* __restrict__ cur_r,
                                               int* __restrict__ csrA, int* __restrict__ csrB) {
    const int is64 = *flag;
    const int e = blockIdx.x * blockDim.x + threadIdx.x;
    if (e >= NE) return;
    const int r = eread(ei, is64, e);
    const int c = eread(ei, is64, NE + e);
    const int pa = atomicAdd(cur_c + c, 1);
    csrA[pa] = r;
    const int pb = atomicAdd(cur_r + r, 1);
    csrB[pb] = c;
}

// ---------- rz1[r][4] = 1 / sum_{e: row=r} ehr1[col_e][4]  (wave per node) ----------
__global__ __launch_bounds__(256) void k_z1(const int* __restrict__ start_r, const int* __restrict__ deg_r,
                                            const int* __restrict__ csrB,
                                            const float* __restrict__ ehr1, float* __restrict__ rz1) {
    const int t = threadIdx.x, lane = t & 63, w = t >> 6;
    const int i = blockIdx.x * 4 + w;
    const int s0 = start_r[i], d = deg_r[i];
    float zx = 0.f, zy = 0.f, zz = 0.f, zw = 0.f;
    for (int p = s0 + lane; p < s0 + d; p += 64) {
        const int c = csrB[p];
        const float4 v = *(const float4*)&ehr1[c * 4];
        zx += v.x; zy += v.y; zz += v.z; zw += v.w;
    }
#pragma unroll
    for (int off = 1; off < 64; off <<= 1) {
        zx += __shfl_xor(zx, off); zy += __shfl_xor(zy, off);
        zz += __shfl_xor(zz, off); zw += __shfl_xor(zw, off);
    }
    if (lane == 0)
        *(float4*)&rz1[i * 4] = make_float4(1.f / zx, 1.f / zy, 1.f / zz, 1.f / zw);
}

// ---------- L1 aggregation on bf16 x, unroll-4 -> xaggb (bf16, [i][h][128]) ----------
__global__ __launch_bounds__(256) void k_agg1(const unsigned short* __restrict__ xb,
                                              const float* __restrict__ ehr1, const float* __restrict__ rz1,
                                              const int* __restrict__ start_c, const int* __restrict__ deg_c,
                                              const int* __restrict__ csrA,
                                              unsigned short* __restrict__ xaggb) {
    const int t = threadIdx.x, lane = t & 63, w = t >> 6;
    const int i = blockIdx.x * 4 + w;
    const float4 er4 = *(const float4*)&ehr1[i * 4];
    const int s0 = start_c[i], dg = deg_c[i];
    float acc[8];
#pragma unroll
    for (int j = 0; j < 8; j++) acc[j] = 0.f;
    int p = s0;
    const int e4 = s0 + (dg & ~3);
    for (; p < e4; p += 4) {
        const int r0 = csrA[p], r1 = csrA[p + 1], r2 = csrA[p + 2], r3 = csrA[p + 3];
        const unsigned v0 = *(const unsigned*)&xb[(size_t)r0 * 128 + lane * 2];
        const unsigned v1 = *(const unsigned*)&xb[(size_t)r1 * 128 + lane * 2];
        const unsigned v2 = *(const unsigned*)&xb[(size_t)r2 * 128 + lane * 2];
        const unsigned v3 = *(const unsigned*)&xb[(size_t)r3 * 128 + lane * 2];
        const float4 z0 = *(const float4*)&rz1[r0 * 4];
        const float4 z1 = *(const float4*)&rz1[r1 * 4];
        const float4 z2 = *(const float4*)&rz1[r2 * 4];
        const float4 z3 = *(const float4*)&rz1[r3 * 4];
        float xa, xbv;
        xa = bflo(v0); xbv = bfhi(v0);
        acc[0] += z0.x * xa; acc[1] += z0.x * xbv;
        acc[2] += z0.y * xa; acc[3] += z0.y * xbv;
        acc[4] += z0.z * xa; acc[5] += z0.z * xbv;
        acc[6] += z0.w * xa; acc[7] += z0.w * xbv;
        xa = bflo(v1); xbv = bfhi(v1);
        acc[0] += z1.x * xa; acc[1] += z1.x * xbv;
        acc[2] += z1.y * xa; acc[3] += z1.y * xbv;
        acc[4] += z1.z * xa; acc[5] += z1.z * xbv;
        acc[6] += z1.w * xa; acc[7] += z1.w * xbv;
        xa = bflo(v2); xbv = bfhi(v2);
        acc[0] += z2.x * xa; acc[1] += z2.x * xbv;
        acc[2] += z2.y * xa; acc[3] += z2.y * xbv;
        acc[4] += z2.z * xa; acc[5] += z2.z * xbv;
        acc[6] += z2.w * xa; acc[7] += z2.w * xbv;
        xa = bflo(v3); xbv = bfhi(v3);
        acc[0] += z3.x * xa; acc[1] += z3.x * xbv;
        acc[2] += z3.y * xa; acc[3] += z3.y * xbv;
        acc[4] += z3.z * xa; acc[5] += z3.z * xbv;
        acc[6] += z3.w * xa; acc[7] += z3.w * xbv;
    }
    for (; p < s0 + dg; ++p) {
        const int r = csrA[p];
        const unsigned v = *(const unsigned*)&xb[(size_t)r * 128 + lane * 2];
        const float4 z = *(const float4*)&rz1[r * 4];
        const float xa = bflo(v), xbv = bfhi(v);
        acc[0] += z.x * xa; acc[1] += z.x * xbv;
        acc[2] += z.y * xa; acc[3] += z.y * xbv;
        acc[4] += z.z * xa; acc[5] += z.z * xbv;
        acc[6] += z.w * xa; acc[7] += z.w * xbv;
    }
    const float ef[4] = {er4.x, er4.y, er4.z, er4.w};
    unsigned short* op = xaggb + (size_t)i * 512 + lane * 2;
#pragma unroll
    for (int h = 0; h < 4; h++) {
        ushort2 st;
        st.x = f2bf(acc[h * 2] * ef[h]);
        st.y = f2bf(acc[h * 2 + 1] * ef[h]);
        *(ushort2*)(op + h * 128) = st;
    }
}

// ---------- MFMA GEMM: y[i,h,:] = xaggb[i,h,:]@W1h; h1m = mean_h ELU(y) ----------
__global__ __launch_bounds__(256) void k_gemmF(const unsigned short* __restrict__ xaggb,
                                               const unsigned short* __restrict__ W1t,
                                               float* __restrict__ h1m) {
    const int t = threadIdx.x, lane = t & 63, w = t >> 6;
    const int n0 = blockIdx.x * 32;          // 32-node tile
    const int r16 = lane & 15, grp = lane >> 4;
    const int jbase = w * 32;                // wave's 32-col slice
    f32x4 hm[2][2];
#pragma unroll
    for (int m = 0; m < 2; m++)
#pragma unroll
        for (int n = 0; n < 2; n++) hm[m][n] = (f32x4)0.f;

#pragma unroll
    for (int h = 0; h < 4; h++) {
        f32x4 acc[2][2];
#pragma unroll
        for (int m = 0; m < 2; m++)
#pragma unroll
            for (int n = 0; n < 2; n++) acc[m][n] = (f32x4)0.f;
#pragma unroll
        for (int kk = 0; kk < 128; kk += 32) {
            const int k0 = kk + grp * 8;
            short8 a0 = *(const short8*)&xaggb[((size_t)(n0 + r16) * 4 + h) * 128 + k0];
            short8 a1 = *(const short8*)&xaggb[((size_t)(n0 + 16 + r16) * 4 + h) * 128 + k0];
            short8 b0 = *(const short8*)&W1t[(size_t)h * 16384 + (jbase + r16) * 128 + k0];
            short8 b1 = *(const short8*)&W1t[(size_t)h * 16384 + (jbase + 16 + r16) * 128 + k0];
            acc[0][0] = __builtin_amdgcn_mfma_f32_16x16x32_bf16(a0, b0, acc[0][0], 0, 0, 0);
            acc[1][0] = __builtin_amdgcn_mfma_f32_16x16x32_bf16(a1, b0, acc[1][0], 0, 0, 0);
            acc[0][1] = __builtin_amdgcn_mfma_f32_16x16x32_bf16(a0, b1, acc[0][1], 0, 0, 0);
            acc[1][1] = __builtin_amdgcn_mfma_f32_16x16x32_bf16(a1, b1, acc[1][1], 0, 0, 0);
        }
#pragma unroll
        for (int m = 0; m < 2; m++)
#pragma unroll
            for (int n = 0; n < 2; n++)
#pragma unroll
                for (int r = 0; r < 4; r++) {
                    const float v = acc[m][n][r];
                    hm[m][n][r] += (v > 0.f) ? v : (__expf(v) - 1.f);  // ELU
                }
    }
    // C/D layout: col = lane&15, row = grp*4 + r  [m89-verified]
#pragma unroll
    for (int m = 0; m < 2; m++)
#pragma unroll
        for (int n = 0; n < 2; n++)
#pragma unroll
            for (int r = 0; r < 4; r++) {
                const int node = n0 + m * 16 + grp * 4 + r;  // pad rows ok (alloc +16)
                const int col = jbase + n * 16 + r16;
                h1m[(size_t)node * 128 + col] = 0.25f * hm[m][n][r];
            }
}

// ---------- Layer-2 GEMM (k-split across lane halves) + exp(hr2) ----------
__global__ __launch_bounds__(256) void k_gemm2(const float* __restrict__ h1m, const float* __restrict__ W2,
                                               const float* __restrict__ a2,
                                               float* __restrict__ h2, float* __restrict__ ehr2) {
    __shared__ float sh[4][128];
    const int t = threadIdx.x, lane = t & 63, w = t >> 6;
    const int i = blockIdx.x * 4 + w;
    sh[w][lane]      = h1m[(size_t)i * 128 + lane];
    sh[w][lane + 64] = h1m[(size_t)i * 128 + 64 + lane];
    __syncthreads();
    const int seg = lane >> 5, c = lane & 31;
    float part = 0.f;
    if (c < 22) {
        const int kb = seg * 64;
        for (int k = kb; k < kb + 64; k++)
            part += sh[w][k] * W2[k * 22 + c];
    }
    part += __shfl_xor(part, 32);   // full dot for col c on both halves
    const float acc = part;
    if (lane < 22) h2[(size_t)i * 22 + lane] = acc;
    float pr = (lane < 22) ? acc * a2[22 + lane] : 0.f;
#pragma unroll
    for (int off = 1; off < 64; off <<= 1)
        pr += __shfl_xor(pr, off);
    if (lane == 0) ehr2[i] = __expf(pr);
}

// ---------- rz2[r] = 1 / sum_{e: row=r} ehr2[col_e]  (wave per node) ----------
__global__ __launch_bounds__(256) void k_z2(const int* __restrict__ start_r, const int* __restrict__ deg_r,
                                            const int* __restrict__ csrB,
                                            const float* __restrict__ ehr2, float* __restrict__ rz2) {
    const int t = threadIdx.x, lane = t & 63, w = t >> 6;
    const int i = blockIdx.x * 4 + w;
    const int s0 = start_r[i], d = deg_r[i];
    float z = 0.f;
    for (int p = s0 + lane; p < s0 + d; p += 64)
        z += ehr2[csrB[p]];
#pragma unroll
    for (int off = 1; off < 64; off <<= 1)
        z += __shfl_xor(z, off);
    if (lane == 0) rz2[i] = 1.f / z;
}

// ---------- L2 aggregation (unroll-4) -> output [N][22] ----------
__global__ __launch_bounds__(256) void k_agg2(const float* __restrict__ h2,
                                              const float* __restrict__ ehr2, const float* __restrict__ rz2,
                                              const int* __restrict__ start_c, const int* __restrict__ deg_c,
                                              const int* __restrict__ csrA,
                                              float* __restrict__ out) {
    const int t = threadIdx.x, lane = t & 63, w = t >> 6;
    const int i = blockIdx.x * 4 + w;
    const int s0 = start_c[i], dg = deg_c[i];
    const float e2 = ehr2[i];
    const int c = (lane < 22) ? lane : 0;
    float acc = 0.f;
    int p = s0;
    const int e4 = s0 + (dg & ~3);
    for (; p < e4; p += 4) {
        const int r0 = csrA[p], r1 = csrA[p + 1], r2 = csrA[p + 2], r3 = csrA[p + 3];
        const float v0 = h2[(size_t)r0 * 22 + c];
        const float v1 = h2[(size_t)r1 * 22 + c];
        const float v2 = h2[(size_t)r2 * 22 + c];
        const float v3 = h2[(size_t)r3 * 22 + c];
        acc += rz2[r0] * v0 + rz2[r1] * v1 + rz2[r2] * v2 + rz2[r3] * v3;
    }
    for (; p < s0 + dg; ++p) {
        const int r = csrA[p];
        acc += rz2[r] * h2[(size_t)r * 22 + c];
    }
    if (lane < 22) out[(size_t)i * 22 + lane] = acc * e2;
}

extern "C" void kernel_launch(void* const* d_in, const int* in_sizes, int n_in,
                              void* d_out, int out_size, void* d_ws, size_t ws_size,
                              hipStream_t stream) {
    const float* x  = (const float*)d_in[0];
    const void*  ei = d_in[1];
    const float* W1 = (const float*)d_in[2];
    const float* a1 = (const float*)d_in[3];
    const float* W2 = (const float*)d_in[4];
    const float* a2 = (const float*)d_in[5];
    float* out = (float*)d_out;

    float* ws = (float*)d_ws;
    unsigned short* xaggb = (unsigned short*)ws;      // 10016*512 ushorts
    float* h1m  = ws + 2600000;                       // 10016*128 (padded)
    float* h2   = ws + 3890000;                       //   220,000
    float* ehr1 = ws + 4110000;                       //    40,000
    float* rz1  = ws + 4150000;                       //    40,000
    float* ehr2 = ws + 4190000;                       //    10,000
    float* rz2  = ws + 4200000;                       //    10,000
    int* deg_c   = (int*)(ws + 4210000);
    int* deg_r   = (int*)(ws + 4220000);
    int* start_c = (int*)(ws + 4230000);
    int* start_r = (int*)(ws + 4240000);
    int* cur_c   = (int*)(ws + 4250000);
    int* cur_r   = (int*)(ws + 4260000);
    int* csrA    = (int*)(ws + 4270000);              //   320,000
    int* csrB    = (int*)(ws + 4590000);              //   320,000
    int* flag    = (int*)(ws + 4910000);
    float* wrf   = ws + 4910064;                      //       512
    unsigned short* W1t = (unsigned short*)(ws + 4911000);  // 65,536 ushorts
    unsigned short* xb  = (unsigned short*)(ws + 4950000);  // 1,280,000 ushorts

    k_detect<<<1, 64, 0, stream>>>((const unsigned int*)ei, flag);
    k_zeroi<<<(20000 + 255) / 256, 256, 0, stream>>>(deg_c, 20000);   // deg_c + deg_r
    k_wprep<<<2, 256, 0, stream>>>(W1, a1, wrf);
    k_w1t<<<256, 256, 0, stream>>>(W1, W1t);
    k_xb<<<2500, 256, 0, stream>>>(x, xb);
    k_hr1<<<2500, 256, 0, stream>>>(x, wrf, ehr1);
    k_hist<<<1250, 256, 0, stream>>>(ei, flag, deg_c, deg_r);
    k_scan2<<<1, 256, 0, stream>>>(deg_c, deg_r, start_c, cur_c, start_r, cur_r);
    k_build<<<1250, 256, 0, stream>>>(ei, flag, cur_c, cur_r, csrA, csrB);
    k_z1<<<2500, 256, 0, stream>>>(start_r, deg_r, csrB, ehr1, rz1);
    k_agg1<<<2500, 256, 0, stream>>>(xb, ehr1, rz1, start_c, deg_c, csrA, xaggb);
    k_gemmF<<<313, 256, 0, stream>>>(xaggb, W1t, h1m);
    k_gemm2<<<2500, 256, 0, stream>>>(h1m, W2, a2, h2, ehr2);
    k_z2<<<2500, 256, 0, stream>>>(start_r, deg_r, csrB, ehr2, rz2);
    k_agg2<<<2500, 256, 0, stream>>>(h2, ehr2, rz2, start_c, deg_c, csrA, out);
}

// Round 6
// 132.986 us; speedup vs baseline: 2.5703x; 1.4118x over previous
//
#include <hip/hip_runtime.h>

#define NN 10000
#define NE 320000

typedef short short8 __attribute__((ext_vector_type(8)));
typedef float f32x4 __attribute__((ext_vector_type(4)));

__device__ __forceinline__ unsigned short f2bf(float f) {
    unsigned u = __float_as_uint(f);
    return (unsigned short)((u + 0x7FFFu + ((u >> 16) & 1u)) >> 16);  // RNE
}
__device__ __forceinline__ float bflo(unsigned v) { return __uint_as_float(v << 16); }
__device__ __forceinline__ float bfhi(unsigned v) { return __uint_as_float(v & 0xffff0000u); }

// ---------- edge index access (int32 vs int64 auto-detect) ----------
__device__ __forceinline__ int eread(const void* p, int is64, int i) {
    if (is64) return (int)((const long long*)p)[i];
    return ((const int*)p)[i];
}

// ---------- fused prep: xb cast | W1t cast | wrf fold | detect | zero ----------
__global__ __launch_bounds__(256) void k_prep(const float* __restrict__ x, const void* __restrict__ ei,
                                              const float* __restrict__ W1, const float* __restrict__ a1,
                                              unsigned short* __restrict__ xb, unsigned short* __restrict__ W1t,
                                              float* __restrict__ wrf, int* __restrict__ flag,
                                              int* __restrict__ degz) {
    const int b = blockIdx.x, t = threadIdx.x;
    if (b < 2500) {                       // xb = bf16(x): 640,000 float2 pairs
        const int g = b * 256 + t;
        const float2 v = *(const float2*)&x[(size_t)g * 2];
        ushort2 o; o.x = f2bf(v.x); o.y = f2bf(v.y);
        *(ushort2*)&xb[(size_t)g * 2] = o;
    } else if (b < 2756) {                // W1t[h][j][k] = bf16(W1[k][h*128+j])
        const int g = (b - 2500) * 256 + t;
        const int h = g >> 14, j = (g >> 7) & 127, k = g & 127;
        W1t[g] = f2bf(W1[(size_t)k * 512 + h * 128 + j]);
    } else if (b < 2758) {                // wrf[h*128+k] = W1[k][h-blk] . a1[h][128:]
        const int g = (b - 2756) * 256 + t;
        const int h = g >> 7, k = g & 127;
        const float* wrow = W1 + (size_t)k * 512 + h * 128;
        const float* av = a1 + h * 256 + 128;
        float s = 0.f;
        for (int d = 0; d < 128; d++) s += wrow[d] * av[d];
        wrf[h * 128 + k] = s;
    } else if (b == 2758) {               // int64-vs-int32 detect
        if (t == 0) {
            const unsigned* idx = (const unsigned*)ei;
            int all0 = 1;
            for (int j = 1; j < 257; j += 2)
                if (idx[j] != 0u) { all0 = 0; break; }
            *flag = all0;
        }
    } else {                              // zero deg_c+deg_r (20,000 ints)
        const int g = (b - 2759) * 256 + t;
        if (g < 20000) degz[g] = 0;
    }
}

// ---------- fused: ehr1 (blocks 0..2499) | hist+rank (blocks 2500..3749) ----------
__global__ __launch_bounds__(256) void k_hr1hist(const float* __restrict__ x, const float* __restrict__ wrf,
                                                 float* __restrict__ ehr1,
                                                 const void* __restrict__ ei, const int* __restrict__ flag,
                                                 int* __restrict__ deg_c, int* __restrict__ deg_r,
                                                 unsigned* __restrict__ rank) {
    __shared__ float ls[512];
    const int b = blockIdx.x, t = threadIdx.x;
    if (b < 2500) {
        const int lane = t & 63, w = t >> 6;
        ls[t] = wrf[t];
        ls[t + 256] = wrf[t + 256];
        __syncthreads();
        const int i = b * 4 + w;
        const float x0 = x[(size_t)i * 128 + lane];
        const float x1 = x[(size_t)i * 128 + 64 + lane];
        float v[4];
#pragma unroll
        for (int h = 0; h < 4; h++)
            v[h] = x0 * ls[h * 128 + lane] + x1 * ls[h * 128 + 64 + lane];
#pragma unroll
        for (int off = 1; off < 64; off <<= 1) {
#pragma unroll
            for (int j = 0; j < 4; j++) v[j] += __shfl_xor(v[j], off);
        }
        if (lane == 0)
            *(float4*)&ehr1[i * 4] = make_float4(__expf(v[0]), __expf(v[1]), __expf(v[2]), __expf(v[3]));
    } else {
        const int is64 = *flag;
        const int e = (b - 2500) * 256 + t;
        const int r = eread(ei, is64, e);
        const int c = eread(ei, is64, NE + e);
        const unsigned rkc = (unsigned)atomicAdd(deg_c + c, 1);
        const unsigned rkr = (unsigned)atomicAdd(deg_r + r, 1);
        rank[e] = rkc | (rkr << 16);
    }
}

// ---------- single-block exclusive scan (deg -> start), two arrays ----------
__device__ void scan_one(const int* __restrict__ deg, int* __restrict__ start, int* ssum) {
    const int t = threadIdx.x;
    int loc[40];
    const int base = t * 40;
    int sum = 0;
#pragma unroll
    for (int j = 0; j < 40; j++) {
        int i = base + j;
        int v = (i < NN) ? deg[i] : 0;
        loc[j] = sum;
        sum += v;
    }
    const int lane = t & 63, w = t >> 6;
    int x = sum;
#pragma unroll
    for (int off = 1; off < 64; off <<= 1) {
        int y = __shfl_up(x, off);
        if (lane >= off) x += y;
    }
    __syncthreads();
    if (lane == 63) ssum[w] = x;
    __syncthreads();
    int woff = 0;
#pragma unroll
    for (int k = 0; k < 4; k++)
        if (k < w) woff += ssum[k];
    const int excl = woff + x - sum;
#pragma unroll
    for (int j = 0; j < 40; j++) {
        int i = base + j;
        if (i < NN) start[i] = excl + loc[j];
    }
}

__global__ __launch_bounds__(256) void k_scan2(const int* __restrict__ deg_c, const int* __restrict__ deg_r,
                                               int* __restrict__ start_c, int* __restrict__ start_r) {
    __shared__ int ssum[4];
    scan_one(deg_c, start_c, ssum);
    scan_one(deg_r, start_r, ssum);
}

// ---------- build dual CSR from precomputed ranks (no atomics) ----------
__global__ __launch_bounds__(256) void k_build(const void* __restrict__ ei, const int* __restrict__ flag,
                                               const unsigned* __restrict__ rank,
                                               const int* __restrict__ start_c, const int* __restrict__ start_r,
                                               int* __restrict__ csrA, int* __restrict__ csrB) {
    const int is64 = *flag;
    const int e = blockIdx.x * blockDim.x + threadIdx.x;
    if (e >= NE) return;
    const int r = eread(ei, is64, e);
    const int c = eread(ei, is64, NE + e);
    const unsigned rk = rank[e];
    csrA[start_c[c] + (int)(rk & 0xffffu)] = r;
    csrB[start_r[r] + (int)(rk >> 16)] = c;
}

// ---------- rz1: 2 nodes per wave, 32 lanes each ----------
__global__ __launch_bounds__(256) void k_z1(const int* __restrict__ start_r, const int* __restrict__ deg_r,
                                            const int* __restrict__ csrB,
                                            const float* __restrict__ ehr1, float* __restrict__ rz1) {
    const int t = threadIdx.x, lane = t & 63, w = t >> 6;
    const int half = lane >> 5, l32 = lane & 31;
    const int i = blockIdx.x * 8 + w * 2 + half;
    const int s0 = start_r[i], d = deg_r[i];
    float zx = 0.f, zy = 0.f, zz = 0.f, zw = 0.f;
    for (int p = s0 + l32; p < s0 + d; p += 32) {
        const int c = csrB[p];
        const float4 v = *(const float4*)&ehr1[c * 4];
        zx += v.x; zy += v.y; zz += v.z; zw += v.w;
    }
#pragma unroll
    for (int off = 1; off < 32; off <<= 1) {
        zx += __shfl_xor(zx, off); zy += __shfl_xor(zy, off);
        zz += __shfl_xor(zz, off); zw += __shfl_xor(zw, off);
    }
    if (l32 == 0)
        *(float4*)&rz1[i * 4] = make_float4(1.f / zx, 1.f / zy, 1.f / zz, 1.f / zw);
}

// ---------- L1 aggregation on bf16 x, unroll-4 -> xaggb (bf16, [i][h][128]) ----------
__global__ __launch_bounds__(256) void k_agg1(const unsigned short* __restrict__ xb,
                                              const float* __restrict__ ehr1, const float* __restrict__ rz1,
                                              const int* __restrict__ start_c, const int* __restrict__ deg_c,
                                              const int* __restrict__ csrA,
                                              unsigned short* __restrict__ xaggb) {
    const int t = threadIdx.x, lane = t & 63, w = t >> 6;
    const int i = blockIdx.x * 4 + w;
    const float4 er4 = *(const float4*)&ehr1[i * 4];
    const int s0 = start_c[i], dg = deg_c[i];
    float acc[8];
#pragma unroll
    for (int j = 0; j < 8; j++) acc[j] = 0.f;
    int p = s0;
    const int e4 = s0 + (dg & ~3);
    for (; p < e4; p += 4) {
        const int r0 = csrA[p], r1 = csrA[p + 1], r2 = csrA[p + 2], r3 = csrA[p + 3];
        const unsigned v0 = *(const unsigned*)&xb[(size_t)r0 * 128 + lane * 2];
        const unsigned v1 = *(const unsigned*)&xb[(size_t)r1 * 128 + lane * 2];
        const unsigned v2 = *(const unsigned*)&xb[(size_t)r2 * 128 + lane * 2];
        const unsigned v3 = *(const unsigned*)&xb[(size_t)r3 * 128 + lane * 2];
        const float4 z0 = *(const float4*)&rz1[r0 * 4];
        const float4 z1 = *(const float4*)&rz1[r1 * 4];
        const float4 z2 = *(const float4*)&rz1[r2 * 4];
        const float4 z3 = *(const float4*)&rz1[r3 * 4];
        float xa, xbv;
        xa = bflo(v0); xbv = bfhi(v0);
        acc[0] += z0.x * xa; acc[1] += z0.x * xbv;
        acc[2] += z0.y * xa; acc[3] += z0.y * xbv;
        acc[4] += z0.z * xa; acc[5] += z0.z * xbv;
        acc[6] += z0.w * xa; acc[7] += z0.w * xbv;
        xa = bflo(v1); xbv = bfhi(v1);
        acc[0] += z1.x * xa; acc[1] += z1.x * xbv;
        acc[2] += z1.y * xa; acc[3] += z1.y * xbv;
        acc[4] += z1.z * xa; acc[5] += z1.z * xbv;
        acc[6] += z1.w * xa; acc[7] += z1.w * xbv;
        xa = bflo(v2); xbv = bfhi(v2);
        acc[0] += z2.x * xa; acc[1] += z2.x * xbv;
        acc[2] += z2.y * xa; acc[3] += z2.y * xbv;
        acc[4] += z2.z * xa; acc[5] += z2.z * xbv;
        acc[6] += z2.w * xa; acc[7] += z2.w * xbv;
        xa = bflo(v3); xbv = bfhi(v3);
        acc[0] += z3.x * xa; acc[1] += z3.x * xbv;
        acc[2] += z3.y * xa; acc[3] += z3.y * xbv;
        acc[4] += z3.z * xa; acc[5] += z3.z * xbv;
        acc[6] += z3.w * xa; acc[7] += z3.w * xbv;
    }
    for (; p < s0 + dg; ++p) {
        const int r = csrA[p];
        const unsigned v = *(const unsigned*)&xb[(size_t)r * 128 + lane * 2];
        const float4 z = *(const float4*)&rz1[r * 4];
        const float xa = bflo(v), xbv = bfhi(v);
        acc[0] += z.x * xa; acc[1] += z.x * xbv;
        acc[2] += z.y * xa; acc[3] += z.y * xbv;
        acc[4] += z.z * xa; acc[5] += z.z * xbv;
        acc[6] += z.w * xa; acc[7] += z.w * xbv;
    }
    const float ef[4] = {er4.x, er4.y, er4.z, er4.w};
    unsigned short* op = xaggb + (size_t)i * 512 + lane * 2;
#pragma unroll
    for (int h = 0; h < 4; h++) {
        ushort2 st;
        st.x = f2bf(acc[h * 2] * ef[h]);
        st.y = f2bf(acc[h * 2 + 1] * ef[h]);
        *(ushort2*)(op + h * 128) = st;
    }
}

// ---------- MFMA GEMM: y[i,h,:] = xaggb[i,h,:]@W1h; h1m = mean_h ELU(y) ----------
__global__ __launch_bounds__(256) void k_gemmF(const unsigned short* __restrict__ xaggb,
                                               const unsigned short* __restrict__ W1t,
                                               float* __restrict__ h1m) {
    const int t = threadIdx.x, lane = t & 63, w = t >> 6;
    const int n0 = blockIdx.x * 32;
    const int r16 = lane & 15, grp = lane >> 4;
    const int jbase = w * 32;
    f32x4 hm[2][2];
#pragma unroll
    for (int m = 0; m < 2; m++)
#pragma unroll
        for (int n = 0; n < 2; n++) hm[m][n] = (f32x4)0.f;

#pragma unroll
    for (int h = 0; h < 4; h++) {
        f32x4 acc[2][2];
#pragma unroll
        for (int m = 0; m < 2; m++)
#pragma unroll
            for (int n = 0; n < 2; n++) acc[m][n] = (f32x4)0.f;
#pragma unroll
        for (int kk = 0; kk < 128; kk += 32) {
            const int k0 = kk + grp * 8;
            short8 a0 = *(const short8*)&xaggb[((size_t)(n0 + r16) * 4 + h) * 128 + k0];
            short8 a1 = *(const short8*)&xaggb[((size_t)(n0 + 16 + r16) * 4 + h) * 128 + k0];
            short8 b0 = *(const short8*)&W1t[(size_t)h * 16384 + (jbase + r16) * 128 + k0];
            short8 b1 = *(const short8*)&W1t[(size_t)h * 16384 + (jbase + 16 + r16) * 128 + k0];
            acc[0][0] = __builtin_amdgcn_mfma_f32_16x16x32_bf16(a0, b0, acc[0][0], 0, 0, 0);
            acc[1][0] = __builtin_amdgcn_mfma_f32_16x16x32_bf16(a1, b0, acc[1][0], 0, 0, 0);
            acc[0][1] = __builtin_amdgcn_mfma_f32_16x16x32_bf16(a0, b1, acc[0][1], 0, 0, 0);
            acc[1][1] = __builtin_amdgcn_mfma_f32_16x16x32_bf16(a1, b1, acc[1][1], 0, 0, 0);
        }
#pragma unroll
        for (int m = 0; m < 2; m++)
#pragma unroll
            for (int n = 0; n < 2; n++)
#pragma unroll
                for (int r = 0; r < 4; r++) {
                    const float v = acc[m][n][r];
                    hm[m][n][r] += (v > 0.f) ? v : (__expf(v) - 1.f);  // ELU
                }
    }
#pragma unroll
    for (int m = 0; m < 2; m++)
#pragma unroll
        for (int n = 0; n < 2; n++)
#pragma unroll
            for (int r = 0; r < 4; r++) {
                const int node = n0 + m * 16 + grp * 4 + r;
                const int col = jbase + n * 16 + r16;
                h1m[(size_t)node * 128 + col] = 0.25f * hm[m][n][r];
            }
}

// ---------- Layer-2 GEMM (k-split across lane halves) + exp(hr2) ----------
__global__ __launch_bounds__(256) void k_gemm2(const float* __restrict__ h1m, const float* __restrict__ W2,
                                               const float* __restrict__ a2,
                                               float* __restrict__ h2, float* __restrict__ ehr2) {
    __shared__ float sh[4][128];
    const int t = threadIdx.x, lane = t & 63, w = t >> 6;
    const int i = blockIdx.x * 4 + w;
    sh[w][lane]      = h1m[(size_t)i * 128 + lane];
    sh[w][lane + 64] = h1m[(size_t)i * 128 + 64 + lane];
    __syncthreads();
    const int seg = lane >> 5, c = lane & 31;
    float part = 0.f;
    if (c < 22) {
        const int kb = seg * 64;
        for (int k = kb; k < kb + 64; k++)
            part += sh[w][k] * W2[k * 22 + c];
    }
    part += __shfl_xor(part, 32);
    const float acc = part;
    if (lane < 22) h2[(size_t)i * 22 + lane] = acc;
    float pr = (lane < 22) ? acc * a2[22 + lane] : 0.f;
#pragma unroll
    for (int off = 1; off < 64; off <<= 1)
        pr += __shfl_xor(pr, off);
    if (lane == 0) ehr2[i] = __expf(pr);
}

// ---------- rz2: 2 nodes per wave ----------
__global__ __launch_bounds__(256) void k_z2(const int* __restrict__ start_r, const int* __restrict__ deg_r,
                                            const int* __restrict__ csrB,
                                            const float* __restrict__ ehr2, float* __restrict__ rz2) {
    const int t = threadIdx.x, lane = t & 63, w = t >> 6;
    const int half = lane >> 5, l32 = lane & 31;
    const int i = blockIdx.x * 8 + w * 2 + half;
    const int s0 = start_r[i], d = deg_r[i];
    float z = 0.f;
    for (int p = s0 + l32; p < s0 + d; p += 32)
        z += ehr2[csrB[p]];
#pragma unroll
    for (int off = 1; off < 32; off <<= 1)
        z += __shfl_xor(z, off);
    if (l32 == 0) rz2[i] = 1.f / z;
}

// ---------- L2 aggregation: 2 nodes per wave, unroll-4 -> out [N][22] ----------
__global__ __launch_bounds__(256) void k_agg2(const float* __restrict__ h2,
                                              const float* __restrict__ ehr2, const float* __restrict__ rz2,
                                              const int* __restrict__ start_c, const int* __restrict__ deg_c,
                                              const int* __restrict__ csrA,
                                              float* __restrict__ out) {
    const int t = threadIdx.x, lane = t & 63, w = t >> 6;
    const int half = lane >> 5, c32 = lane & 31;
    const int i = blockIdx.x * 8 + w * 2 + half;
    const int s0 = start_c[i], dg = deg_c[i];
    const float e2 = ehr2[i];
    const int c = (c32 < 22) ? c32 : 0;
    float acc = 0.f;
    int p = s0;
    const int e4 = s0 + (dg & ~3);
    for (; p < e4; p += 4) {
        const int r0 = csrA[p], r1 = csrA[p + 1], r2 = csrA[p + 2], r3 = csrA[p + 3];
        const float v0 = h2[(size_t)r0 * 22 + c];
        const float v1 = h2[(size_t)r1 * 22 + c];
        const float v2 = h2[(size_t)r2 * 22 + c];
        const float v3 = h2[(size_t)r3 * 22 + c];
        acc += rz2[r0] * v0 + rz2[r1] * v1 + rz2[r2] * v2 + rz2[r3] * v3;
    }
    for (; p < s0 + dg; ++p) {
        const int r = csrA[p];
        acc += rz2[r] * h2[(size_t)r * 22 + c];
    }
    if (c32 < 22) out[(size_t)i * 22 + c32] = acc * e2;
}

extern "C" void kernel_launch(void* const* d_in, const int* in_sizes, int n_in,
                              void* d_out, int out_size, void* d_ws, size_t ws_size,
                              hipStream_t stream) {
    const float* x  = (const float*)d_in[0];
    const void*  ei = d_in[1];
    const float* W1 = (const float*)d_in[2];
    const float* a1 = (const float*)d_in[3];
    const float* W2 = (const float*)d_in[4];
    const float* a2 = (const float*)d_in[5];
    float* out = (float*)d_out;

    float* ws = (float*)d_ws;
    unsigned short* xaggb = (unsigned short*)ws;        // 10016*512 ushorts
    float* h1m  = ws + 2600000;                         // 10016*128 (padded)
    float* h2   = ws + 3890000;                         //   220,000
    float* ehr1 = ws + 4110000;                         //    40,000
    float* rz1  = ws + 4150000;                         //    40,000
    float* ehr2 = ws + 4190000;                         //    10,000
    float* rz2  = ws + 4200000;                         //    10,000
    int* deg_c   = (int*)(ws + 4210000);                //    10,000
    int* deg_r   = (int*)(ws + 4220000);                //    10,000 (contiguous after deg_c)
    int* start_c = (int*)(ws + 4230000);
    int* start_r = (int*)(ws + 4240000);
    int* csrA    = (int*)(ws + 4250000);                //   320,000
    int* csrB    = (int*)(ws + 4570000);                //   320,000
    int* flag    = (int*)(ws + 4890000);
    float* wrf   = ws + 4890064;                        //       512
    unsigned short* W1t = (unsigned short*)(ws + 4891000);  //  65,536 ushorts
    unsigned short* xb  = (unsigned short*)(ws + 4924000);  // 1,280,000 ushorts
    unsigned* rank = (unsigned*)(ws + 5564000);             //   320,000 uints

    k_prep<<<2838, 256, 0, stream>>>(x, ei, W1, a1, xb, W1t, wrf, flag, deg_c);
    k_hr1hist<<<3750, 256, 0, stream>>>(x, wrf, ehr1, ei, flag, deg_c, deg_r, rank);
    k_scan2<<<1, 256, 0, stream>>>(deg_c, deg_r, start_c, start_r);
    k_build<<<1250, 256, 0, stream>>>(ei, flag, rank, start_c, start_r, csrA, csrB);
    k_z1<<<1250, 256, 0, stream>>>(start_r, deg_r, csrB, ehr1, rz1);
    k_agg1<<<2500, 256, 0, stream>>>(xb, ehr1, rz1, start_c, deg_c, csrA, xaggb);
    k_gemmF<<<313, 256, 0, stream>>>(xaggb, W1t, h1m);
    k_gemm2<<<2500, 256, 0, stream>>>(h1m, W2, a2, h2, ehr2);
    k_z2<<<1250, 256, 0, stream>>>(start_r, deg_r, csrB, ehr2, rz2);
    k_agg2<<<1250, 256, 0, stream>>>(h2, ehr2, rz2, start_c, deg_c, csrA, out);
}

// Round 9
// 124.861 us; speedup vs baseline: 2.7375x; 1.0651x over previous
//
#include <hip/hip_runtime.h>

#define NN 10000
#define NE 320000

typedef short short8 __attribute__((ext_vector_type(8)));
typedef float f32x4 __attribute__((ext_vector_type(4)));

__device__ __forceinline__ unsigned short f2bf(float f) {
    unsigned u = __float_as_uint(f);
    return (unsigned short)((u + 0x7FFFu + ((u >> 16) & 1u)) >> 16);  // RNE
}
__device__ __forceinline__ float bflo(unsigned v) { return __uint_as_float(v << 16); }
__device__ __forceinline__ float bfhi(unsigned v) { return __uint_as_float(v & 0xffff0000u); }
__device__ __forceinline__ float bf1(unsigned short v) { return __uint_as_float(((unsigned)v) << 16); }

__device__ __forceinline__ int eread(const void* p, int is64, int i) {
    if (is64) return (int)((const long long*)p)[i];
    return ((const int*)p)[i];
}

// ---------- prep0: W1t cast | wrf fold | detect | zero deg ----------
__global__ __launch_bounds__(256) void k_prep0(const void* __restrict__ ei,
                                               const float* __restrict__ W1, const float* __restrict__ a1,
                                               unsigned short* __restrict__ W1t, float* __restrict__ wrf,
                                               int* __restrict__ flag, int* __restrict__ degz) {
    const int b = blockIdx.x, t = threadIdx.x;
    if (b < 256) {                        // W1t[h][j][k] = bf16(W1[k][h*128+j])
        const int g = b * 256 + t;
        const int h = g >> 14, j = (g >> 7) & 127, k = g & 127;
        W1t[g] = f2bf(W1[(size_t)k * 512 + h * 128 + j]);
    } else if (b < 258) {                 // wrf[h*128+k] = W1[k][h-blk] . a1[h][128:]
        const int g = (b - 256) * 256 + t;
        const int h = g >> 7, k = g & 127;
        const float* wrow = W1 + (size_t)k * 512 + h * 128;
        const float* av = a1 + h * 256 + 128;
        float s = 0.f;
        for (int d = 0; d < 128; d++) s += wrow[d] * av[d];
        wrf[h * 128 + k] = s;
    } else if (b == 258) {                // int64-vs-int32 detect
        if (t == 0) {
            const unsigned* idx = (const unsigned*)ei;
            int all0 = 1;
            for (int j = 1; j < 257; j += 2)
                if (idx[j] != 0u) { all0 = 0; break; }
            *flag = all0;
        }
    } else {                              // zero deg_c+deg_r (20,000 ints)
        const int g = (b - 259) * 256 + t;
        if (g < 20000) degz[g] = 0;
    }
}

// ---------- pre: blocks 0..2499 = xb cast + ehr1; 2500..3749 = hist+rank ----------
__global__ __launch_bounds__(256) void k_pre(const float* __restrict__ x, const float* __restrict__ wrf,
                                             unsigned short* __restrict__ xb, float* __restrict__ ehr1,
                                             const void* __restrict__ ei, const int* __restrict__ flag,
                                             int* __restrict__ deg_c, int* __restrict__ deg_r,
                                             unsigned* __restrict__ rank) {
    __shared__ float ls[512];
    const int b = blockIdx.x, t = threadIdx.x;
    if (b < 2500) {
        const int lane = t & 63, w = t >> 6;
        ls[t] = wrf[t];
        ls[t + 256] = wrf[t + 256];
        __syncthreads();
        const int i = b * 4 + w;
        const float x0 = x[(size_t)i * 128 + lane];
        const float x1 = x[(size_t)i * 128 + 64 + lane];
        xb[(size_t)i * 128 + lane]      = f2bf(x0);
        xb[(size_t)i * 128 + 64 + lane] = f2bf(x1);
        float v[4];
#pragma unroll
        for (int h = 0; h < 4; h++)
            v[h] = x0 * ls[h * 128 + lane] + x1 * ls[h * 128 + 64 + lane];
#pragma unroll
        for (int off = 1; off < 64; off <<= 1) {
#pragma unroll
            for (int j = 0; j < 4; j++) v[j] += __shfl_xor(v[j], off);
        }
        if (lane == 0)
            *(float4*)&ehr1[i * 4] = make_float4(__expf(v[0]), __expf(v[1]), __expf(v[2]), __expf(v[3]));
    } else {
        const int is64 = *flag;
        const int e = (b - 2500) * 256 + t;
        const int r = eread(ei, is64, e);
        const int c = eread(ei, is64, NE + e);
        const unsigned rkc = (unsigned)atomicAdd(deg_c + c, 1);
        const unsigned rkr = (unsigned)atomicAdd(deg_r + r, 1);
        rank[e] = rkc | (rkr << 16);
    }
}

// ---------- single-block (1024 thr) exclusive scan of deg_c and deg_r ----------
__device__ void scan_one_1k(const int* __restrict__ deg, int* __restrict__ start, int* ssum) {
    const int t = threadIdx.x;           // 0..1023
    int loc[10];
    const int base = t * 10;
    int sum = 0;
#pragma unroll
    for (int j = 0; j < 10; j++) {
        int i = base + j;
        int v = (i < NN) ? deg[i] : 0;
        loc[j] = sum;
        sum += v;
    }
    const int lane = t & 63, w = t >> 6; // w in 0..15
    int xi = sum;
#pragma unroll
    for (int off = 1; off < 64; off <<= 1) {
        int y = __shfl_up(xi, off);
        if (lane >= off) xi += y;
    }
    __syncthreads();
    if (lane == 63) ssum[w] = xi;
    __syncthreads();
    int woff = 0;
#pragma unroll
    for (int k = 0; k < 16; k++)
        if (k < w) woff += ssum[k];
    const int excl = woff + xi - sum;
#pragma unroll
    for (int j = 0; j < 10; j++) {
        int i = base + j;
        if (i < NN) start[i] = excl + loc[j];
    }
}

__global__ __launch_bounds__(1024) void k_scan2(const int* __restrict__ deg_c, const int* __restrict__ deg_r,
                                                int* __restrict__ start_c, int* __restrict__ start_r) {
    __shared__ int ssum[16];
    scan_one_1k(deg_c, start_c, ssum);
    __syncthreads();
    scan_one_1k(deg_r, start_r, ssum);
}

// ---------- build dual CSR from precomputed ranks (no atomics) ----------
__global__ __launch_bounds__(256) void k_build(const void* __restrict__ ei, const int* __restrict__ flag,
                                               const unsigned* __restrict__ rank,
                                               const int* __restrict__ start_c, const int* __restrict__ start_r,
                                               int* __restrict__ csrA, int* __restrict__ csrB) {
    const int is64 = *flag;
    const int e = blockIdx.x * blockDim.x + threadIdx.x;
    if (e >= NE) return;
    const int r = eread(ei, is64, e);
    const int c = eread(ei, is64, NE + e);
    const unsigned rk = rank[e];
    csrA[start_c[c] + (int)(rk & 0xffffu)] = r;
    csrB[start_r[r] + (int)(rk >> 16)] = c;
}

// ---------- rz1: 2 nodes per wave, 32 lanes each ----------
__global__ __launch_bounds__(256) void k_z1(const int* __restrict__ start_r, const int* __restrict__ deg_r,
                                            const int* __restrict__ csrB,
                                            const float* __restrict__ ehr1, float* __restrict__ rz1) {
    const int t = threadIdx.x, lane = t & 63, w = t >> 6;
    const int half = lane >> 5, l32 = lane & 31;
    const int i = blockIdx.x * 8 + w * 2 + half;
    const int s0 = start_r[i], d = deg_r[i];
    float zx = 0.f, zy = 0.f, zz = 0.f, zw = 0.f;
    for (int p = s0 + l32; p < s0 + d; p += 32) {
        const int c = csrB[p];
        const float4 v = *(const float4*)&ehr1[c * 4];
        zx += v.x; zy += v.y; zz += v.z; zw += v.w;
    }
#pragma unroll
    for (int off = 1; off < 32; off <<= 1) {
        zx += __shfl_xor(zx, off); zy += __shfl_xor(zy, off);
        zz += __shfl_xor(zz, off); zw += __shfl_xor(zw, off);
    }
    if (l32 == 0)
        *(float4*)&rz1[i * 4] = make_float4(1.f / zx, 1.f / zy, 1.f / zz, 1.f / zw);
}

// ---------- L1 aggregation on bf16 x, unroll-8 -> xaggb (bf16, [i][h][128]) ----------
__global__ __launch_bounds__(256) void k_agg1(const unsigned short* __restrict__ xb,
                                              const float* __restrict__ ehr1, const float* __restrict__ rz1,
                                              const int* __restrict__ start_c, const int* __restrict__ deg_c,
                                              const int* __restrict__ csrA,
                                              unsigned short* __restrict__ xaggb) {
    const int t = threadIdx.x, lane = t & 63, w = t >> 6;
    const int i = blockIdx.x * 4 + w;
    const float4 er4 = *(const float4*)&ehr1[i * 4];
    const int s0 = start_c[i], dg = deg_c[i];
    float acc[8];
#pragma unroll
    for (int j = 0; j < 8; j++) acc[j] = 0.f;
    int p = s0;
    const int e8 = s0 + (dg & ~7);
    for (; p < e8; p += 8) {
        int rr[8]; unsigned vv[8]; float4 zz[8];
#pragma unroll
        for (int q = 0; q < 8; q++) rr[q] = csrA[p + q];
#pragma unroll
        for (int q = 0; q < 8; q++) vv[q] = *(const unsigned*)&xb[(size_t)rr[q] * 128 + lane * 2];
#pragma unroll
        for (int q = 0; q < 8; q++) zz[q] = *(const float4*)&rz1[rr[q] * 4];
#pragma unroll
        for (int q = 0; q < 8; q++) {
            const float xa = bflo(vv[q]), xbv = bfhi(vv[q]);
            acc[0] += zz[q].x * xa; acc[1] += zz[q].x * xbv;
            acc[2] += zz[q].y * xa; acc[3] += zz[q].y * xbv;
            acc[4] += zz[q].z * xa; acc[5] += zz[q].z * xbv;
            acc[6] += zz[q].w * xa; acc[7] += zz[q].w * xbv;
        }
    }
    for (; p < s0 + dg; ++p) {
        const int r = csrA[p];
        const unsigned v = *(const unsigned*)&xb[(size_t)r * 128 + lane * 2];
        const float4 z = *(const float4*)&rz1[r * 4];
        const float xa = bflo(v), xbv = bfhi(v);
        acc[0] += z.x * xa; acc[1] += z.x * xbv;
        acc[2] += z.y * xa; acc[3] += z.y * xbv;
        acc[4] += z.z * xa; acc[5] += z.z * xbv;
        acc[6] += z.w * xa; acc[7] += z.w * xbv;
    }
    const float ef[4] = {er4.x, er4.y, er4.z, er4.w};
    unsigned short* op = xaggb + (size_t)i * 512 + lane * 2;
#pragma unroll
    for (int h = 0; h < 4; h++) {
        ushort2 st;
        st.x = f2bf(acc[h * 2] * ef[h]);
        st.y = f2bf(acc[h * 2 + 1] * ef[h]);
        *(ushort2*)(op + h * 128) = st;
    }
}

// ---------- MFMA GEMM: y[i,h,:] = xaggb[i,h,:]@W1h; h1m = mean_h ELU(y) ----------
__global__ __launch_bounds__(256) void k_gemmF(const unsigned short* __restrict__ xaggb,
                                               const unsigned short* __restrict__ W1t,
                                               float* __restrict__ h1m) {
    const int t = threadIdx.x, lane = t & 63, w = t >> 6;
    const int n0 = blockIdx.x * 32;
    const int r16 = lane & 15, grp = lane >> 4;
    const int jbase = w * 32;
    f32x4 hm[2][2];
#pragma unroll
    for (int m = 0; m < 2; m++)
#pragma unroll
        for (int n = 0; n < 2; n++) hm[m][n] = (f32x4)0.f;

#pragma unroll
    for (int h = 0; h < 4; h++) {
        f32x4 acc[2][2];
#pragma unroll
        for (int m = 0; m < 2; m++)
#pragma unroll
            for (int n = 0; n < 2; n++) acc[m][n] = (f32x4)0.f;
#pragma unroll
        for (int kk = 0; kk < 128; kk += 32) {
            const int k0 = kk + grp * 8;
            short8 a0 = *(const short8*)&xaggb[((size_t)(n0 + r16) * 4 + h) * 128 + k0];
            short8 a1 = *(const short8*)&xaggb[((size_t)(n0 + 16 + r16) * 4 + h) * 128 + k0];
            short8 b0 = *(const short8*)&W1t[(size_t)h * 16384 + (jbase + r16) * 128 + k0];
            short8 b1 = *(const short8*)&W1t[(size_t)h * 16384 + (jbase + 16 + r16) * 128 + k0];
            acc[0][0] = __builtin_amdgcn_mfma_f32_16x16x32_bf16(a0, b0, acc[0][0], 0, 0, 0);
            acc[1][0] = __builtin_amdgcn_mfma_f32_16x16x32_bf16(a1, b0, acc[1][0], 0, 0, 0);
            acc[0][1] = __builtin_amdgcn_mfma_f32_16x16x32_bf16(a0, b1, acc[0][1], 0, 0, 0);
            acc[1][1] = __builtin_amdgcn_mfma_f32_16x16x32_bf16(a1, b1, acc[1][1], 0, 0, 0);
        }
#pragma unroll
        for (int m = 0; m < 2; m++)
#pragma unroll
            for (int n = 0; n < 2; n++)
#pragma unroll
                for (int r = 0; r < 4; r++) {
                    const float v = acc[m][n][r];
                    hm[m][n][r] += (v > 0.f) ? v : (__expf(v) - 1.f);  // ELU
                }
    }
#pragma unroll
    for (int m = 0; m < 2; m++)
#pragma unroll
        for (int n = 0; n < 2; n++)
#pragma unroll
            for (int r = 0; r < 4; r++) {
                const int node = n0 + m * 16 + grp * 4 + r;
                const int col = jbase + n * 16 + r16;
                h1m[(size_t)node * 128 + col] = 0.25f * hm[m][n][r];
            }
}

// ---------- Layer-2 GEMM (k-split across lane halves) + exp(hr2) ----------
__global__ __launch_bounds__(256) void k_gemm2(const float* __restrict__ h1m, const float* __restrict__ W2,
                                               const float* __restrict__ a2,
                                               float* __restrict__ h2, float* __restrict__ ehr2) {
    __shared__ float sh[4][128];
    const int t = threadIdx.x, lane = t & 63, w = t >> 6;
    const int i = blockIdx.x * 4 + w;
    sh[w][lane]      = h1m[(size_t)i * 128 + lane];
    sh[w][lane + 64] = h1m[(size_t)i * 128 + 64 + lane];
    __syncthreads();
    const int seg = lane >> 5, c = lane & 31;
    float part = 0.f;
    if (c < 22) {
        const int kb = seg * 64;
        for (int k = kb; k < kb + 64; k++)
            part += sh[w][k] * W2[k * 22 + c];
    }
    part += __shfl_xor(part, 32);
    const float acc = part;
    if (lane < 22) h2[(size_t)i * 22 + lane] = acc;
    float pr = (lane < 22) ? acc * a2[22 + lane] : 0.f;
#pragma unroll
    for (int off = 1; off < 64; off <<= 1)
        pr += __shfl_xor(pr, off);
    if (lane == 0) ehr2[i] = __expf(pr);
}

// ---------- z2 + fold: h2s[i][c] = bf16(h2[i][c] / z2[i]) ----------
__global__ __launch_bounds__(256) void k_z2s(const int* __restrict__ start_r, const int* __restrict__ deg_r,
                                             const int* __restrict__ csrB,
                                             const float* __restrict__ ehr2, const float* __restrict__ h2,
                                             unsigned short* __restrict__ h2s) {
    const int t = threadIdx.x, lane = t & 63, w = t >> 6;
    const int half = lane >> 5, l32 = lane & 31;
    const int i = blockIdx.x * 8 + w * 2 + half;
    const int s0 = start_r[i], d = deg_r[i];
    float z = 0.f;
    for (int p = s0 + l32; p < s0 + d; p += 32)
        z += ehr2[csrB[p]];
#pragma unroll
    for (int off = 1; off < 32; off <<= 1)
        z += __shfl_xor(z, off);          // all 32 lanes now hold the sum
    const float rz = 1.f / z;
    if (l32 < 22)
        h2s[(size_t)i * 22 + l32] = f2bf(h2[(size_t)i * 22 + l32] * rz);
}

// ---------- L2 aggregation: 2 nodes/wave, bf16 h2s gather, unroll-4 ----------
__global__ __launch_bounds__(256) void k_agg2(const unsigned short* __restrict__ h2s,
                                              const float* __restrict__ ehr2,
                                              const int* __restrict__ start_c, const int* __restrict__ deg_c,
                                              const int* __restrict__ csrA,
                                              float* __restrict__ out) {
    const int t = threadIdx.x, lane = t & 63, w = t >> 6;
    const int half = lane >> 5, c32 = lane & 31;
    const int i = blockIdx.x * 8 + w * 2 + half;
    const int s0 = start_c[i], dg = deg_c[i];
    const float e2 = ehr2[i];
    const int c = (c32 < 22) ? c32 : 0;
    float acc = 0.f;
    int p = s0;
    const int e4 = s0 + (dg & ~3);
    for (; p < e4; p += 4) {
        const int r0 = csrA[p], r1 = csrA[p + 1], r2 = csrA[p + 2], r3 = csrA[p + 3];
        const float v0 = bf1(h2s[(size_t)r0 * 22 + c]);
        const float v1 = bf1(h2s[(size_t)r1 * 22 + c]);
        const float v2 = bf1(h2s[(size_t)r2 * 22 + c]);
        const float v3 = bf1(h2s[(size_t)r3 * 22 + c]);
        acc += v0 + v1 + v2 + v3;
    }
    for (; p < s0 + dg; ++p) {
        const int r = csrA[p];
        acc += bf1(h2s[(size_t)r * 22 + c]);
    }
    if (c32 < 22) out[(size_t)i * 22 + c32] = acc * e2;
}

extern "C" void kernel_launch(void* const* d_in, const int* in_sizes, int n_in,
                              void* d_out, int out_size, void* d_ws, size_t ws_size,
                              hipStream_t stream) {
    const float* x  = (const float*)d_in[0];
    const void*  ei = d_in[1];
    const float* W1 = (const float*)d_in[2];
    const float* a1 = (const float*)d_in[3];
    const float* W2 = (const float*)d_in[4];
    const float* a2 = (const float*)d_in[5];
    float* out = (float*)d_out;

    float* ws = (float*)d_ws;
    unsigned short* xaggb = (unsigned short*)ws;        // 10016*512 ushorts
    float* h1m  = ws + 2600000;                         // 10016*128 (padded)
    float* h2   = ws + 3890000;                         //   220,000
    float* ehr1 = ws + 4110000;                         //    40,000
    float* rz1  = ws + 4150000;                         //    40,000
    float* ehr2 = ws + 4190000;                         //    10,000
    unsigned short* h2s = (unsigned short*)(ws + 4200000);  // 220,000 ushorts
    int* deg_c   = (int*)(ws + 4310000);                //    10,000
    int* deg_r   = (int*)(ws + 4320000);                //    10,000 (contiguous after deg_c)
    int* start_c = (int*)(ws + 4330000);
    int* start_r = (int*)(ws + 4340000);
    int* csrA    = (int*)(ws + 4350000);                //   320,000
    int* csrB    = (int*)(ws + 4670000);                //   320,000
    int* flag    = (int*)(ws + 4990000);
    float* wrf   = ws + 4990064;                        //       512
    unsigned short* W1t = (unsigned short*)(ws + 4991000);  //  65,536 ushorts
    unsigned short* xb  = (unsigned short*)(ws + 5024000);  // 1,280,000 ushorts
    unsigned* rank = (unsigned*)(ws + 5664000);             //   320,000 uints

    k_prep0<<<338, 256, 0, stream>>>(ei, W1, a1, W1t, wrf, flag, deg_c);
    k_pre<<<3750, 256, 0, stream>>>(x, wrf, xb, ehr1, ei, flag, deg_c, deg_r, rank);
    k_scan2<<<1, 1024, 0, stream>>>(deg_c, deg_r, start_c, start_r);
    k_build<<<1250, 256, 0, stream>>>(ei, flag, rank, start_c, start_r, csrA, csrB);
    k_z1<<<1250, 256, 0, stream>>>(start_r, deg_r, csrB, ehr1, rz1);
    k_agg1<<<2500, 256, 0, stream>>>(xb, ehr1, rz1, start_c, deg_c, csrA, xaggb);
    k_gemmF<<<313, 256, 0, stream>>>(xaggb, W1t, h1m);
    k_gemm2<<<2500, 256, 0, stream>>>(h1m, W2, a2, h2, ehr2);
    k_z2s<<<1250, 256, 0, stream>>>(start_r, deg_r, csrB, ehr2, h2, h2s);
    k_agg2<<<1250, 256, 0, stream>>>(h2s, ehr2, start_c, deg_c, csrA, out);
}